// Round 1
// baseline (2624.290 us; speedup 1.0000x reference)
//
#include <hip/hip_runtime.h>
#include <math.h>

#define NNODES 8192
#define DIN 561
#define DH 256
#define NEDGE 262144
#define FCDIM 512
#define MLD 576   // padded leading dim for M = HC @ W0^T

enum { AC_FEAT = 0, AC_STRUCT, AC_SE, AC_CONS, AC_SREG, AC_CQ, AC_DENSE, AC_NUM };
#define NBUCKET 64

// ---- output offsets (floats) ----
#define OFF_COEF ((size_t)6)
#define OFF_CONS ((size_t)6 + (size_t)NNODES * NNODES)
#define OFF_SREG (OFF_CONS + 1)
#define OFF_CQ   (OFF_CONS + 2)
#define OFF_H1   (OFF_CONS + 3)
#define OFF_H2   (OFF_H1 + (size_t)NNODES * DH)

// ============================================================
// GEMM NN: C[MxNn] = A[MxK] @ B[KxNn]   (64x64 tile, BK=32, 256 thr, 4x4 micro)
// ============================================================
__global__ __launch_bounds__(256) void gate_gemm_nn(
    const float* __restrict__ A, const float* __restrict__ B,
    float* __restrict__ C, int M, int Nn, int K, int lda, int ldb, int ldc)
{
    __shared__ float As[32][68];
    __shared__ float Bs[32][68];
    const int bm = blockIdx.x * 64, bn = blockIdx.y * 64;
    const int tid = threadIdx.x;
    const int tx = tid & 15, ty = tid >> 4;
    float acc[4][4] = {};
    for (int k0 = 0; k0 < K; k0 += 32) {
        const int ar = tid >> 2, ak = (tid & 3) * 8;
        #pragma unroll
        for (int j = 0; j < 8; ++j) {
            const int gk = k0 + ak + j;
            As[ak + j][ar] = (gk < K) ? A[(size_t)(bm + ar) * lda + gk] : 0.f;
        }
        const int bk = tid >> 3, bn0 = (tid & 7) * 8;
        const int gk = k0 + bk;
        #pragma unroll
        for (int j = 0; j < 8; ++j) {
            const int gn = bn + bn0 + j;
            Bs[bk][bn0 + j] = (gk < K && gn < Nn) ? B[(size_t)gk * ldb + gn] : 0.f;
        }
        __syncthreads();
        #pragma unroll
        for (int k = 0; k < 32; ++k) {
            float a[4], b[4];
            #pragma unroll
            for (int i = 0; i < 4; ++i) a[i] = As[k][ty * 4 + i];
            #pragma unroll
            for (int j = 0; j < 4; ++j) b[j] = Bs[k][tx * 4 + j];
            #pragma unroll
            for (int i = 0; i < 4; ++i)
                #pragma unroll
                for (int j = 0; j < 4; ++j) acc[i][j] = fmaf(a[i], b[j], acc[i][j]);
        }
        __syncthreads();
    }
    #pragma unroll
    for (int i = 0; i < 4; ++i) {
        const int gm = bm + ty * 4 + i;
        if (gm >= M) continue;
        #pragma unroll
        for (int j = 0; j < 4; ++j) {
            const int gn = bn + tx * 4 + j;
            if (gn < Nn) C[(size_t)gm * ldc + gn] = acc[i][j];
        }
    }
}

// ============================================================
// GEMM BT: C[MxNn] = A[MxK,lda] @ B^T   where B is [Nn x K] row-major.
// Optional bias[Nn]. K must be a multiple of 32 (K=256 here).
// ============================================================
__global__ __launch_bounds__(256) void gate_gemm_bt(
    const float* __restrict__ A, int lda,
    const float* __restrict__ B,
    const float* __restrict__ bias,
    float* __restrict__ C, int ldc, int M, int Nn, int K)
{
    __shared__ float As[32][68];
    __shared__ float Bs[32][68];
    const int bm = blockIdx.x * 64, bn = blockIdx.y * 64;
    const int tid = threadIdx.x;
    const int tx = tid & 15, ty = tid >> 4;
    float acc[4][4] = {};
    for (int k0 = 0; k0 < K; k0 += 32) {
        const int ar = tid >> 2, ak = (tid & 3) * 8;
        #pragma unroll
        for (int j = 0; j < 8; ++j)
            As[ak + j][ar] = A[(size_t)(bm + ar) * lda + k0 + ak + j];
        // B: rows = output cols (n), need Bs[k][n]
        const int br = tid >> 2, bk = (tid & 3) * 8;  // br: n index 0..63
        const int gn = bn + br;
        #pragma unroll
        for (int j = 0; j < 8; ++j)
            Bs[bk + j][br] = (gn < Nn) ? B[(size_t)gn * K + k0 + bk + j] : 0.f;
        __syncthreads();
        #pragma unroll
        for (int k = 0; k < 32; ++k) {
            float a[4], b[4];
            #pragma unroll
            for (int i = 0; i < 4; ++i) a[i] = As[k][ty * 4 + i];
            #pragma unroll
            for (int j = 0; j < 4; ++j) b[j] = Bs[k][tx * 4 + j];
            #pragma unroll
            for (int i = 0; i < 4; ++i)
                #pragma unroll
                for (int j = 0; j < 4; ++j) acc[i][j] = fmaf(a[i], b[j], acc[i][j]);
        }
        __syncthreads();
    }
    #pragma unroll
    for (int i = 0; i < 4; ++i) {
        const int gm = bm + ty * 4 + i;
        if (gm >= M) continue;
        #pragma unroll
        for (int j = 0; j < 4; ++j) {
            const int gn = bn + tx * 4 + j;
            if (gn < Nn) {
                float v = acc[i][j];
                if (bias) v += bias[gn];
                C[(size_t)gm * ldc + gn] = v;
            }
        }
    }
}

// ============================================================
// Big GEMM: HC[N x 512] = (W - diag(W)) @ Hcat[N x 512]
// BM=128, BN=64, BK=16, 256 threads, 8x4 micro-tile.
// ============================================================
__global__ __launch_bounds__(256) void gate_gemm_coef(
    const float* __restrict__ W, const float* __restrict__ B, float* __restrict__ C)
{
    __shared__ float As[16][132];   // 132*4 = 528 bytes/row -> 16B-aligned rows
    __shared__ float Bs[16][64];
    const int bm = blockIdx.x * 128, bn = blockIdx.y * 64;
    const int tid = threadIdx.x;
    const int tx = tid & 15, ty = tid >> 4;
    float acc[8][4] = {};
    for (int k0 = 0; k0 < NNODES; k0 += 16) {
        const int ar = tid >> 1, ak = (tid & 1) * 8;
        const float* Ap = W + (size_t)(bm + ar) * NNODES + k0 + ak;
        const bool maskdiag = (k0 + 15 >= bm) && (k0 <= bm + 127);
        if (maskdiag) {
            #pragma unroll
            for (int j = 0; j < 8; ++j) {
                float v = Ap[j];
                if (bm + ar == k0 + ak + j) v = 0.f;
                As[ak + j][ar] = v;
            }
        } else {
            const float4 v0 = *(const float4*)(Ap);
            const float4 v1 = *(const float4*)(Ap + 4);
            As[ak + 0][ar] = v0.x; As[ak + 1][ar] = v0.y;
            As[ak + 2][ar] = v0.z; As[ak + 3][ar] = v0.w;
            As[ak + 4][ar] = v1.x; As[ak + 5][ar] = v1.y;
            As[ak + 6][ar] = v1.z; As[ak + 7][ar] = v1.w;
        }
        const int bk = tid >> 4, bn0 = (tid & 15) * 4;
        *(float4*)&Bs[bk][bn0] = *(const float4*)(B + (size_t)(k0 + bk) * 512 + bn + bn0);
        __syncthreads();
        #pragma unroll
        for (int k = 0; k < 16; ++k) {
            float a[8], b[4];
            #pragma unroll
            for (int i = 0; i < 8; ++i) a[i] = As[k][ty * 8 + i];
            #pragma unroll
            for (int j = 0; j < 4; ++j) b[j] = Bs[k][tx * 4 + j];
            #pragma unroll
            for (int i = 0; i < 8; ++i)
                #pragma unroll
                for (int j = 0; j < 4; ++j) acc[i][j] = fmaf(a[i], b[j], acc[i][j]);
        }
        __syncthreads();
    }
    #pragma unroll
    for (int i = 0; i < 8; ++i) {
        float4 v = make_float4(acc[i][0], acc[i][1], acc[i][2], acc[i][3]);
        *(float4*)(C + (size_t)(bm + ty * 8 + i) * 512 + bn + tx * 4) = v;
    }
}

// ============================================================
// f1 = H @ v00, f2 = H @ v10 : one wave per row
// ============================================================
__global__ __launch_bounds__(256) void gate_f1f2(
    const float* __restrict__ H, const float* __restrict__ v0,
    const float* __restrict__ v1, float* __restrict__ f1, float* __restrict__ f2)
{
    const int wave = threadIdx.x >> 6, lane = threadIdx.x & 63;
    const int row = blockIdx.x * 4 + wave;
    const float4 h = ((const float4*)(H + (size_t)row * DH))[lane];
    const float4 a = ((const float4*)v0)[lane];
    const float4 b = ((const float4*)v1)[lane];
    float s1 = h.x * a.x + h.y * a.y + h.z * a.z + h.w * a.w;
    float s2 = h.x * b.x + h.y * b.y + h.z * b.z + h.w * b.w;
    #pragma unroll
    for (int off = 32; off; off >>= 1) {
        s1 += __shfl_down(s1, off);
        s2 += __shfl_down(s2, off);
    }
    if (lane == 0) { f1[row] = s1; f2[row] = s2; }
}

// ============================================================
// CSR build: histogram, scan, scatter
// ============================================================
__global__ void gate_hist(const int* __restrict__ rows, int* __restrict__ cnt)
{
    const int e = blockIdx.x * 256 + threadIdx.x;
    if (e < NEDGE) atomicAdd(&cnt[rows[e]], 1);
}

__global__ __launch_bounds__(256) void gate_scan(
    const int* __restrict__ cnt, int* __restrict__ rowptr, int* __restrict__ cur)
{
    __shared__ int part[256];
    const int t = threadIdx.x;
    const int base = t * 32;
    int local[32];
    int s = 0;
    #pragma unroll
    for (int i = 0; i < 32; ++i) { local[i] = s; s += cnt[base + i]; }
    part[t] = s;
    __syncthreads();
    for (int d = 1; d < 256; d <<= 1) {
        const int add = (t >= d) ? part[t - d] : 0;
        __syncthreads();
        part[t] += add;
        __syncthreads();
    }
    const int excl = (t == 0) ? 0 : part[t - 1];
    #pragma unroll
    for (int i = 0; i < 32; ++i) {
        const int v = excl + local[i];
        rowptr[base + i] = v;
        cur[base + i] = v;
    }
    if (t == 255) rowptr[NNODES] = excl + s;
}

__global__ void gate_scatter(const int* __restrict__ rows, const int* __restrict__ cols,
                             int* __restrict__ cur, int* __restrict__ col_p)
{
    const int e = blockIdx.x * 256 + threadIdx.x;
    if (e < NEDGE) {
        const int slot = atomicAdd(&cur[rows[e]], 1);
        col_p[slot] = cols[e];
    }
}

// ============================================================
// attention: per-row sigmoid + segment softmax (one wave per row)
// ============================================================
__global__ __launch_bounds__(64) void gate_att(
    const int* __restrict__ rowptr, const int* __restrict__ col_p,
    const float* __restrict__ f1, const float* __restrict__ f2,
    float* __restrict__ att_p)
{
    const int row = blockIdx.x;
    const int s0 = rowptr[row], s1 = rowptr[row + 1];
    const int lane = threadIdx.x;
    const float f1r = f1[row];
    float mx = -1e30f;
    for (int s = s0 + lane; s < s1; s += 64) {
        float u = f1r + f2[col_p[s]];
        u = 1.f / (1.f + expf(-u));
        att_p[s] = u;
        mx = fmaxf(mx, u);
    }
    #pragma unroll
    for (int off = 32; off; off >>= 1) mx = fmaxf(mx, __shfl_xor(mx, off));
    float sum = 0.f;
    for (int s = s0 + lane; s < s1; s += 64) {
        const float ex = expf(att_p[s] - mx);
        att_p[s] = ex;
        sum += ex;
    }
    #pragma unroll
    for (int off = 32; off; off >>= 1) sum += __shfl_xor(sum, off);
    const float inv = 1.f / (sum + 1e-12f);
    for (int s = s0 + lane; s < s1; s += 64) att_p[s] *= inv;
}

// ============================================================
// H_enc[row] = sum att * H[col]  (one block per row, thread = feature)
// writes Hcat (stride 512, +voff) and the d_out copy
// ============================================================
__global__ __launch_bounds__(256) void gate_spmm_henc(
    const int* __restrict__ rowptr, const int* __restrict__ col_p,
    const float* __restrict__ att_p, const float* __restrict__ H,
    float* __restrict__ Hcat, float* __restrict__ outp, int voff)
{
    const int row = blockIdx.x, d = threadIdx.x;
    const int s0 = rowptr[row], s1 = rowptr[row + 1];
    float acc = 0.f;
    for (int s = s0; s < s1; ++s)
        acc = fmaf(att_p[s], H[(size_t)col_p[s] * DH + d], acc);
    Hcat[(size_t)row * 512 + voff + d] = acc;
    outp[(size_t)row * DH + d] = acc;
}

// ============================================================
// coef write + S_Regular + Cq_loss (64x64 tiles, Theta read transposed via LDS)
// ============================================================
__global__ __launch_bounds__(256) void gate_coef(
    const float* __restrict__ W, const float* __restrict__ Theta,
    float* __restrict__ coef_out, double* __restrict__ accumB)
{
    __shared__ float Ts[64][65];
    __shared__ float red[256];
    const int i0 = blockIdx.x * 64, j0 = blockIdx.y * 64;
    const int t = threadIdx.x;
    const int c = t & 63, rgrp = t >> 6;
    #pragma unroll
    for (int jj = 0; jj < 16; ++jj) {
        const int jr = rgrp * 16 + jj;
        Ts[jr][c] = Theta[(size_t)(j0 + jr) * NNODES + i0 + c];
    }
    __syncthreads();
    float sreg = 0.f, cq = 0.f;
    #pragma unroll
    for (int ii = 0; ii < 16; ++ii) {
        const int rr = rgrp * 16 + ii;
        const int gi = i0 + rr, gj = j0 + c;
        const float w = W[(size_t)gi * NNODES + gj];
        const float cf = (gi == gj) ? 0.f : w;
        coef_out[(size_t)gi * NNODES + gj] = cf;
        const float a = fabsf(cf);
        sreg += a;
        cq = fmaf(a, fabsf(Ts[c][rr]), cq);
    }
    const int bucket = (blockIdx.x + blockIdx.y) & (NBUCKET - 1);
    red[t] = sreg; __syncthreads();
    for (int d = 128; d; d >>= 1) { if (t < d) red[t] += red[t + d]; __syncthreads(); }
    if (t == 0) atomicAdd(&accumB[bucket * AC_NUM + AC_SREG], (double)red[0]);
    __syncthreads();
    red[t] = cq; __syncthreads();
    for (int d = 128; d; d >>= 1) { if (t < d) red[t] += red[t + d]; __syncthreads(); }
    if (t == 0) atomicAdd(&accumB[bucket * AC_NUM + AC_CQ], (double)red[0]);
}

// ============================================================
// SE: sum((Hcat - HC)^2) over N*512
// ============================================================
__global__ __launch_bounds__(256) void gate_se(
    const float* __restrict__ Hcat, const float* __restrict__ HC,
    double* __restrict__ accumB)
{
    __shared__ float red[256];
    float part = 0.f;
    for (size_t i = (size_t)blockIdx.x * 256 + threadIdx.x;
         i < (size_t)NNODES * 512; i += (size_t)2048 * 256) {
        const float d = Hcat[i] - HC[i];
        part = fmaf(d, d, part);
    }
    const int t = threadIdx.x;
    red[t] = part; __syncthreads();
    for (int d = 128; d; d >>= 1) { if (t < d) red[t] += red[t + d]; __syncthreads(); }
    if (t == 0) atomicAdd(&accumB[(blockIdx.x & (NBUCKET - 1)) * AC_NUM + AC_SE], (double)red[0]);
}

// ============================================================
// consistent: sum((Henc1 - Henc2)^2)
// ============================================================
__global__ __launch_bounds__(256) void gate_cons(
    const float* __restrict__ Hcat, double* __restrict__ accumB)
{
    __shared__ float red[256];
    float part = 0.f;
    for (size_t i = (size_t)blockIdx.x * 256 + threadIdx.x;
         i < (size_t)NNODES * DH; i += (size_t)1024 * 256) {
        const size_t row = i >> 8;
        const int d = (int)(i & 255);
        const float v = Hcat[row * 512 + d] - Hcat[row * 512 + 256 + d];
        part = fmaf(v, v, part);
    }
    const int t = threadIdx.x;
    red[t] = part; __syncthreads();
    for (int d = 128; d; d >>= 1) { if (t < d) red[t] += red[t + d]; __syncthreads(); }
    if (t == 0) atomicAdd(&accumB[(blockIdx.x & (NBUCKET - 1)) * AC_NUM + AC_CONS], (double)red[0]);
}

// ============================================================
// recon + features loss: per row, recompute X_recon row in regs, accumulate (X - Xr)^2
// ============================================================
__global__ __launch_bounds__(256) void gate_recon_loss(
    const int* __restrict__ rowptr, const int* __restrict__ col_p,
    const float* __restrict__ att_p, const float* __restrict__ Mbuf,
    const float* __restrict__ X, double* __restrict__ accumB)
{
    __shared__ float red[256];
    const int row = blockIdx.x, t = threadIdx.x;
    const int s0 = rowptr[row], s1 = rowptr[row + 1];
    float acc0 = 0.f, acc1 = 0.f, acc2 = 0.f;
    for (int s = s0; s < s1; ++s) {
        const float a = att_p[s];
        const float* mr = Mbuf + (size_t)col_p[s] * MLD;
        acc0 = fmaf(a, mr[t], acc0);
        acc1 = fmaf(a, mr[t + 256], acc1);
        if (t < DIN - 512) acc2 = fmaf(a, mr[t + 512], acc2);
    }
    const float* xr = X + (size_t)row * DIN;
    const float d0 = xr[t] - acc0;
    const float d1 = xr[t + 256] - acc1;
    float part = d0 * d0 + d1 * d1;
    if (t < DIN - 512) { const float d2 = xr[t + 512] - acc2; part = fmaf(d2, d2, part); }
    red[t] = part; __syncthreads();
    for (int d = 128; d; d >>= 1) { if (t < d) red[t] += red[t + d]; __syncthreads(); }
    if (t == 0) atomicAdd(&accumB[(blockIdx.x & (NBUCKET - 1)) * AC_NUM + AC_FEAT], (double)red[0]);
}

// ============================================================
// structure loss: sum softplus(-dot(Henc[S], Henc[R])) , wave per edge
// ============================================================
__global__ __launch_bounds__(256) void gate_struct(
    const int* __restrict__ S, const int* __restrict__ R,
    const float* __restrict__ Hcat, int voff, double* __restrict__ accumB)
{
    __shared__ float red[4];
    const int wave = threadIdx.x >> 6, lane = threadIdx.x & 63;
    const int widx = blockIdx.x * 4 + wave;
    float part = 0.f;
    for (int e = widx; e < NEDGE; e += gridDim.x * 4) {
        const float4 av = ((const float4*)(Hcat + (size_t)S[e] * 512 + voff))[lane];
        const float4 bv = ((const float4*)(Hcat + (size_t)R[e] * 512 + voff))[lane];
        float d = av.x * bv.x + av.y * bv.y + av.z * bv.z + av.w * bv.w;
        #pragma unroll
        for (int off = 32; off; off >>= 1) d += __shfl_xor(d, off);
        if (lane == 0) {
            const float x = d;
            const float sp = (x > 0.f) ? log1pf(expf(-x)) : (-x + log1pf(expf(x)));
            part += sp;
        }
    }
    if (lane == 0) red[wave] = part;
    __syncthreads();
    if (threadIdx.x == 0)
        atomicAdd(&accumB[(blockIdx.x & (NBUCKET - 1)) * AC_NUM + AC_STRUCT],
                  (double)(red[0] + red[1] + red[2] + red[3]));
}

// ============================================================
// z head + cross-entropy: wave per row; fcz_w staged in LDS
// ============================================================
__global__ __launch_bounds__(256) void gate_zhead(
    const float* __restrict__ tbuf, const float* __restrict__ fczw,
    const float* __restrict__ fczb, const int* __restrict__ p,
    double* __restrict__ accumB)
{
    __shared__ float wz[6 * 512];
    __shared__ float bz[6];
    __shared__ float red[4];
    for (int i = threadIdx.x; i < 6 * 512; i += 256) wz[i] = fczw[i];
    if (threadIdx.x < 6) bz[threadIdx.x] = fczb[threadIdx.x];
    __syncthreads();
    const int wave = threadIdx.x >> 6, lane = threadIdx.x & 63;
    const int row = blockIdx.x * 4 + wave;
    const float* tr = tbuf + (size_t)row * 512;
    float part[6] = {};
    for (int j = lane; j < 512; j += 64) {
        const float tv = tr[j];
        #pragma unroll
        for (int c = 0; c < 6; ++c) part[c] = fmaf(tv, wz[c * 512 + j], part[c]);
    }
    #pragma unroll
    for (int c = 0; c < 6; ++c)
        #pragma unroll
        for (int off = 32; off; off >>= 1) part[c] += __shfl_xor(part[c], off);
    if (lane == 0) {
        float z[6], mx = -1e30f;
        #pragma unroll
        for (int c = 0; c < 6; ++c) { z[c] = part[c] + bz[c]; mx = fmaxf(mx, z[c]); }
        float se = 0.f;
        #pragma unroll
        for (int c = 0; c < 6; ++c) se += expf(z[c] - mx);
        const float lse = mx + logf(se);
        red[wave] = lse - z[p[row]];
    }
    __syncthreads();
    if (threadIdx.x == 0)
        atomicAdd(&accumB[(blockIdx.x & (NBUCKET - 1)) * AC_NUM + AC_DENSE],
                  (double)(red[0] + red[1] + red[2] + red[3]));
}

// ============================================================
// final: sum buckets, combine, write scalar outputs
// ============================================================
__global__ void gate_final(const double* __restrict__ accumB, float* __restrict__ out)
{
    if (threadIdx.x == 0 && blockIdx.x == 0) {
        double acc[AC_NUM];
        for (int i = 0; i < AC_NUM; ++i) acc[i] = 0.0;
        for (int b = 0; b < NBUCKET; ++b)
            for (int i = 0; i < AC_NUM; ++i) acc[i] += accumB[b * AC_NUM + i];
        const double feat = acc[AC_FEAT], st = acc[AC_STRUCT];
        const double se = 0.5 * acc[AC_SE];
        const double cons = acc[AC_CONS], sreg = acc[AC_SREG];
        const double cq = acc[AC_CQ], dl = acc[AC_DENSE];
        const double pre = feat + st + 10.0 * se + 0.01 * cons + sreg;
        const double loss = 0.01 * feat + st + 10.0 * se + 0.001 * cons + sreg
                          + 5.0 * cq + 5.0 * dl;
        out[0] = (float)pre;
        out[1] = (float)loss;
        out[2] = (float)dl;
        out[3] = (float)feat;
        out[4] = (float)st;
        out[5] = (float)se;
        out[OFF_CONS] = (float)cons;
        out[OFF_SREG] = (float)sreg;
        out[OFF_CQ]   = (float)cq;
    }
}

// ============================================================
extern "C" void kernel_launch(void* const* d_in, const int* in_sizes, int n_in,
                              void* d_out, int out_size, void* d_ws, size_t ws_size,
                              hipStream_t stream)
{
    (void)in_sizes; (void)n_in; (void)out_size; (void)ws_size;
    const float* X      = (const float*)d_in[0];
    const float* X2     = (const float*)d_in[1];
    const float* Theta  = (const float*)d_in[2];
    const int*   Aidx   = (const int*)d_in[3];
    const int*   A2idx  = (const int*)d_in[5];
    const int*   S      = (const int*)d_in[7];
    const int*   R      = (const int*)d_in[8];
    const int*   S2     = (const int*)d_in[9];
    const int*   R2     = (const int*)d_in[10];
    const int*   p      = (const int*)d_in[11];
    const float* W0     = (const float*)d_in[13];
    const float* v00    = (const float*)d_in[14];
    const float* v10    = (const float*)d_in[15];
    const float* weight = (const float*)d_in[16];
    const float* fc1_w  = (const float*)d_in[17];
    const float* fc1_b  = (const float*)d_in[18];
    const float* fcz_w  = (const float*)d_in[19];
    const float* fcz_b  = (const float*)d_in[20];
    const float* fc2_w  = (const float*)d_in[21];
    const float* fc2_b  = (const float*)d_in[22];
    const float* fcz2_w = (const float*)d_in[23];
    const float* fcz2_b = (const float*)d_in[24];
    float* out = (float*)d_out;

    // ---- workspace carve ----
    char* wp = (char*)d_ws;
    auto alloc = [&](size_t bytes) -> void* {
        void* r = (void*)wp;
        wp += (bytes + 255) & ~(size_t)255;
        return r;
    };
    float* H1    = (float*)alloc((size_t)NNODES * DH * 4);
    float* H2    = (float*)alloc((size_t)NNODES * DH * 4);
    float* Hcat  = (float*)alloc((size_t)NNODES * 512 * 4);
    float* HCcat = (float*)alloc((size_t)NNODES * 512 * 4);
    float* Mbuf  = (float*)alloc((size_t)NNODES * MLD * 4);  // also reused as tbuf
    float* tbuf  = Mbuf;                                     // disjoint lifetimes
    float* f1a = (float*)alloc(NNODES * 4);
    float* f2a = (float*)alloc(NNODES * 4);
    float* f1b = (float*)alloc(NNODES * 4);
    float* f2b = (float*)alloc(NNODES * 4);
    int* cnt    = (int*)alloc(2 * NNODES * 4);
    int* rowptr = (int*)alloc(2 * (NNODES + 1) * 4);
    int* cur    = (int*)alloc(2 * NNODES * 4);
    int* colp   = (int*)alloc(2 * (size_t)NEDGE * 4);
    float* attp = (float*)alloc(2 * (size_t)NEDGE * 4);
    double* accumB = (double*)alloc(NBUCKET * AC_NUM * 8);

    hipMemsetAsync(cnt, 0, 2 * NNODES * 4, stream);
    hipMemsetAsync(accumB, 0, NBUCKET * AC_NUM * 8, stream);

    // encode: H = X @ W0 (both views)
    gate_gemm_nn<<<dim3(NNODES / 64, DH / 64), 256, 0, stream>>>(
        X, W0, H1, NNODES, DH, DIN, DIN, DH, DH);
    gate_gemm_nn<<<dim3(NNODES / 64, DH / 64), 256, 0, stream>>>(
        X2, W0, H2, NNODES, DH, DIN, DIN, DH, DH);
    gate_f1f2<<<NNODES / 4, 256, 0, stream>>>(H1, v00, v10, f1a, f2a);
    gate_f1f2<<<NNODES / 4, 256, 0, stream>>>(H2, v00, v10, f1b, f2b);

    // CSR build
    gate_hist<<<NEDGE / 256, 256, 0, stream>>>(Aidx, cnt);
    gate_hist<<<NEDGE / 256, 256, 0, stream>>>(A2idx, cnt + NNODES);
    gate_scan<<<1, 256, 0, stream>>>(cnt, rowptr, cur);
    gate_scan<<<1, 256, 0, stream>>>(cnt + NNODES, rowptr + NNODES + 1, cur + NNODES);
    gate_scatter<<<NEDGE / 256, 256, 0, stream>>>(Aidx, Aidx + NEDGE, cur, colp);
    gate_scatter<<<NEDGE / 256, 256, 0, stream>>>(A2idx, A2idx + NEDGE, cur + NNODES, colp + NEDGE);

    // attention + aggregation
    gate_att<<<NNODES, 64, 0, stream>>>(rowptr, colp, f1a, f2a, attp);
    gate_att<<<NNODES, 64, 0, stream>>>(rowptr + NNODES + 1, colp + NEDGE, f1b, f2b, attp + NEDGE);
    gate_spmm_henc<<<NNODES, 256, 0, stream>>>(rowptr, colp, attp, H1, Hcat, out + OFF_H1, 0);
    gate_spmm_henc<<<NNODES, 256, 0, stream>>>(rowptr + NNODES + 1, colp + NEDGE, attp + NEDGE,
                                               H2, Hcat, out + OFF_H2, 256);

    // coef write + S_Regular + Cq
    gate_coef<<<dim3(NNODES / 64, NNODES / 64), 256, 0, stream>>>(
        weight, Theta, out + OFF_COEF, accumB);

    // HC = coef @ [Henc1 | Henc2]
    gate_gemm_coef<<<dim3(NNODES / 128, 512 / 64), 256, 0, stream>>>(weight, Hcat, HCcat);

    gate_se<<<2048, 256, 0, stream>>>(Hcat, HCcat, accumB);
    gate_cons<<<1024, 256, 0, stream>>>(Hcat, accumB);

    // view 1: M = HC1 @ W0^T ; features loss
    gate_gemm_bt<<<dim3(NNODES / 64, (DIN + 63) / 64), 256, 0, stream>>>(
        HCcat, 512, W0, nullptr, Mbuf, MLD, NNODES, DIN, DH);
    gate_recon_loss<<<NNODES, 256, 0, stream>>>(rowptr, colp, attp, Mbuf, X, accumB);
    // view 2
    gate_gemm_bt<<<dim3(NNODES / 64, (DIN + 63) / 64), 256, 0, stream>>>(
        HCcat + 256, 512, W0, nullptr, Mbuf, MLD, NNODES, DIN, DH);
    gate_recon_loss<<<NNODES, 256, 0, stream>>>(rowptr + NNODES + 1, colp + NEDGE,
                                                attp + NEDGE, Mbuf, X2, accumB);

    // dense heads (reuse Mbuf region as tbuf — lifetimes disjoint)
    gate_gemm_bt<<<dim3(NNODES / 64, FCDIM / 64), 256, 0, stream>>>(
        Hcat, 512, fc1_w, fc1_b, tbuf, 512, NNODES, FCDIM, DH);
    gate_zhead<<<NNODES / 4, 256, 0, stream>>>(tbuf, fcz_w, fcz_b, p, accumB);
    gate_gemm_bt<<<dim3(NNODES / 64, FCDIM / 64), 256, 0, stream>>>(
        Hcat + 256, 512, fc2_w, fc2_b, tbuf, 512, NNODES, FCDIM, DH);
    gate_zhead<<<NNODES / 4, 256, 0, stream>>>(tbuf, fcz2_w, fcz2_b, p, accumB);

    // structure losses
    gate_struct<<<2048, 256, 0, stream>>>(S, R, Hcat, 0, accumB);
    gate_struct<<<2048, 256, 0, stream>>>(S2, R2, Hcat, 256, accumB);

    gate_final<<<1, 64, 0, stream>>>(accumB, out);
}

// Round 2
// 1819.118 us; speedup vs baseline: 1.4426x; 1.4426x over previous
//
#include <hip/hip_runtime.h>
#include <math.h>

#define NNODES 8192
#define DIN 561
#define DH 256
#define NEDGE 262144
#define FCDIM 512
#define MLD 576   // padded leading dim for M = HC @ W0^T

enum { AC_FEAT = 0, AC_STRUCT, AC_SE, AC_CONS, AC_SREG, AC_CQ, AC_DENSE, AC_NUM };
#define NBUCKET 64

// ---- output offsets (floats) ----
#define OFF_COEF ((size_t)6)
#define OFF_CONS ((size_t)6 + (size_t)NNODES * NNODES)
#define OFF_SREG (OFF_CONS + 1)
#define OFF_CQ   (OFF_CONS + 2)
#define OFF_H1   (OFF_CONS + 3)
#define OFF_H2   (OFF_H1 + (size_t)NNODES * DH)

typedef short bf16x8 __attribute__((ext_vector_type(8)));
typedef float f32x4  __attribute__((ext_vector_type(4)));

__device__ __forceinline__ unsigned short f2bf(float f) {
    union { float f; unsigned int u; } v; v.f = f;
    const unsigned int u = v.u;
    return (unsigned short)((u + 0x7fffu + ((u >> 16) & 1u)) >> 16);  // RNE
}

__device__ __forceinline__ void gload_lds16(const void* g, void* l) {
    __builtin_amdgcn_global_load_lds(
        (const __attribute__((address_space(1))) unsigned int*)g,
        (__attribute__((address_space(3))) unsigned int*)l, 16, 0, 0);
}

// ============================================================
// GEMM NN: C[MxNn] = A[MxK] @ B[KxNn]   (64x64 tile, BK=32, 256 thr, 4x4 micro)
// ============================================================
__global__ __launch_bounds__(256) void gate_gemm_nn(
    const float* __restrict__ A, const float* __restrict__ B,
    float* __restrict__ C, int M, int Nn, int K, int lda, int ldb, int ldc)
{
    __shared__ float As[32][68];
    __shared__ float Bs[32][68];
    const int bm = blockIdx.x * 64, bn = blockIdx.y * 64;
    const int tid = threadIdx.x;
    const int tx = tid & 15, ty = tid >> 4;
    float acc[4][4] = {};
    for (int k0 = 0; k0 < K; k0 += 32) {
        const int ar = tid >> 2, ak = (tid & 3) * 8;
        #pragma unroll
        for (int j = 0; j < 8; ++j) {
            const int gk = k0 + ak + j;
            As[ak + j][ar] = (gk < K) ? A[(size_t)(bm + ar) * lda + gk] : 0.f;
        }
        const int bk = tid >> 3, bn0 = (tid & 7) * 8;
        const int gk = k0 + bk;
        #pragma unroll
        for (int j = 0; j < 8; ++j) {
            const int gn = bn + bn0 + j;
            Bs[bk][bn0 + j] = (gk < K && gn < Nn) ? B[(size_t)gk * ldb + gn] : 0.f;
        }
        __syncthreads();
        #pragma unroll
        for (int k = 0; k < 32; ++k) {
            float a[4], b[4];
            #pragma unroll
            for (int i = 0; i < 4; ++i) a[i] = As[k][ty * 4 + i];
            #pragma unroll
            for (int j = 0; j < 4; ++j) b[j] = Bs[k][tx * 4 + j];
            #pragma unroll
            for (int i = 0; i < 4; ++i)
                #pragma unroll
                for (int j = 0; j < 4; ++j) acc[i][j] = fmaf(a[i], b[j], acc[i][j]);
        }
        __syncthreads();
    }
    #pragma unroll
    for (int i = 0; i < 4; ++i) {
        const int gm = bm + ty * 4 + i;
        if (gm >= M) continue;
        #pragma unroll
        for (int j = 0; j < 4; ++j) {
            const int gn = bn + tx * 4 + j;
            if (gn < Nn) C[(size_t)gm * ldc + gn] = acc[i][j];
        }
    }
}

// ============================================================
// GEMM BT: C[MxNn] = A[MxK,lda] @ B^T   where B is [Nn x K] row-major.
// ============================================================
__global__ __launch_bounds__(256) void gate_gemm_bt(
    const float* __restrict__ A, int lda,
    const float* __restrict__ B,
    const float* __restrict__ bias,
    float* __restrict__ C, int ldc, int M, int Nn, int K)
{
    __shared__ float As[32][68];
    __shared__ float Bs[32][68];
    const int bm = blockIdx.x * 64, bn = blockIdx.y * 64;
    const int tid = threadIdx.x;
    const int tx = tid & 15, ty = tid >> 4;
    float acc[4][4] = {};
    for (int k0 = 0; k0 < K; k0 += 32) {
        const int ar = tid >> 2, ak = (tid & 3) * 8;
        #pragma unroll
        for (int j = 0; j < 8; ++j)
            As[ak + j][ar] = A[(size_t)(bm + ar) * lda + k0 + ak + j];
        const int br = tid >> 2, bk = (tid & 3) * 8;
        const int gn = bn + br;
        #pragma unroll
        for (int j = 0; j < 8; ++j)
            Bs[bk + j][br] = (gn < Nn) ? B[(size_t)gn * K + k0 + bk + j] : 0.f;
        __syncthreads();
        #pragma unroll
        for (int k = 0; k < 32; ++k) {
            float a[4], b[4];
            #pragma unroll
            for (int i = 0; i < 4; ++i) a[i] = As[k][ty * 4 + i];
            #pragma unroll
            for (int j = 0; j < 4; ++j) b[j] = Bs[k][tx * 4 + j];
            #pragma unroll
            for (int i = 0; i < 4; ++i)
                #pragma unroll
                for (int j = 0; j < 4; ++j) acc[i][j] = fmaf(a[i], b[j], acc[i][j]);
        }
        __syncthreads();
    }
    #pragma unroll
    for (int i = 0; i < 4; ++i) {
        const int gm = bm + ty * 4 + i;
        if (gm >= M) continue;
        #pragma unroll
        for (int j = 0; j < 4; ++j) {
            const int gn = bn + tx * 4 + j;
            if (gn < Nn) {
                float v = acc[i][j];
                if (bias) v += bias[gn];
                C[(size_t)gm * ldc + gn] = v;
            }
        }
    }
}

// ============================================================
// fp32 fallback: HC = (W - diag) @ Hcat  (only if workspace too small for MFMA)
// ============================================================
__global__ __launch_bounds__(256) void gate_gemm_coef(
    const float* __restrict__ W, const float* __restrict__ B, float* __restrict__ C)
{
    __shared__ float As[16][132];
    __shared__ float Bs[16][64];
    const int bm = blockIdx.x * 128, bn = blockIdx.y * 64;
    const int tid = threadIdx.x;
    const int tx = tid & 15, ty = tid >> 4;
    float acc[8][4] = {};
    for (int k0 = 0; k0 < NNODES; k0 += 16) {
        const int ar = tid >> 1, ak = (tid & 1) * 8;
        const float* Ap = W + (size_t)(bm + ar) * NNODES + k0 + ak;
        const bool maskdiag = (k0 + 15 >= bm) && (k0 <= bm + 127);
        if (maskdiag) {
            #pragma unroll
            for (int j = 0; j < 8; ++j) {
                float v = Ap[j];
                if (bm + ar == k0 + ak + j) v = 0.f;
                As[ak + j][ar] = v;
            }
        } else {
            const float4 v0 = *(const float4*)(Ap);
            const float4 v1 = *(const float4*)(Ap + 4);
            As[ak + 0][ar] = v0.x; As[ak + 1][ar] = v0.y;
            As[ak + 2][ar] = v0.z; As[ak + 3][ar] = v0.w;
            As[ak + 4][ar] = v1.x; As[ak + 5][ar] = v1.y;
            As[ak + 6][ar] = v1.z; As[ak + 7][ar] = v1.w;
        }
        const int bk = tid >> 4, bn0 = (tid & 15) * 4;
        *(float4*)&Bs[bk][bn0] = *(const float4*)(B + (size_t)(k0 + bk) * 512 + bn + bn0);
        __syncthreads();
        #pragma unroll
        for (int k = 0; k < 16; ++k) {
            float a[8], b[4];
            #pragma unroll
            for (int i = 0; i < 8; ++i) a[i] = As[k][ty * 8 + i];
            #pragma unroll
            for (int j = 0; j < 4; ++j) b[j] = Bs[k][tx * 4 + j];
            #pragma unroll
            for (int i = 0; i < 8; ++i)
                #pragma unroll
                for (int j = 0; j < 4; ++j) acc[i][j] = fmaf(a[i], b[j], acc[i][j]);
        }
        __syncthreads();
    }
    #pragma unroll
    for (int i = 0; i < 8; ++i) {
        float4 v = make_float4(acc[i][0], acc[i][1], acc[i][2], acc[i][3]);
        *(float4*)(C + (size_t)(bm + ty * 8 + i) * 512 + bn + tx * 4) = v;
    }
}

// ============================================================
// MFMA GEMM: HC[8192x512] = Wbf(diag-zeroed bf16) @ Bt^T
//   A = Wbf [8192][8192] bf16 row-major (K-contiguous)
//   Bt = Hcat^T [512][8192] bf16 row-major (K-contiguous)
// 128x64 tile, BK=64, 4 waves (2x2), 16x16x32 bf16 MFMA, double-buffered LDS,
// XOR-swizzled LDS layout via pre-swizzled global source (rule #21).
// ============================================================
#define BMT 128
#define BNT 64
#define BKT 64

__global__ __launch_bounds__(256, 2) void gate_gemm_coef_mfma(
    const unsigned short* __restrict__ Wbf,
    const unsigned short* __restrict__ Bt,
    float* __restrict__ C)
{
    __shared__ __align__(16) unsigned short Asm[2][BMT * BKT];  // 16 KB each
    __shared__ __align__(16) unsigned short Bsm[2][BNT * BKT];  // 8 KB each
    const int tid = threadIdx.x;
    const int wid = tid >> 6, lane = tid & 63;
    const int bm = blockIdx.x * BMT, bn = blockIdx.y * BNT;
    const int wr = wid >> 1, wc = wid & 1;

    // ---- staging descriptors (global source pre-swizzled, LDS dest linear) ----
    const int l3 = lane >> 3, l7 = lane & 7;
    const int kxor = (l7 ^ l3) * 8;  // r&7 == lane>>3 for every chunk
    const unsigned short* aSrc[4];
    int aDst[4];
    #pragma unroll
    for (int i = 0; i < 4; ++i) {
        const int c = wid + i * 4;           // chunk 0..15 -> rows 8c..8c+7
        const int r = c * 8 + l3;
        aSrc[i] = Wbf + (size_t)(bm + r) * NNODES + kxor;
        aDst[i] = c * 512;                   // shorts (1024 B per chunk)
    }
    const unsigned short* bSrc[2];
    int bDst[2];
    #pragma unroll
    for (int i = 0; i < 2; ++i) {
        const int c = wid + i * 4;           // chunk 0..7 -> rows 8c..8c+7
        const int r = c * 8 + l3;
        bSrc[i] = Bt + (size_t)(bn + r) * NNODES + kxor;
        bDst[i] = c * 512;
    }

    // ---- swizzled read offsets (in shorts), loop-invariant ----
    const int l15 = lane & 15, l4 = lane >> 4;
    int aOff[2][4], bOff[2][2];
    #pragma unroll
    for (int ks = 0; ks < 2; ++ks) {
        const int u = ks * 4 + l4;
        #pragma unroll
        for (int mr = 0; mr < 4; ++mr) {
            const int r = wr * 64 + mr * 16 + l15;
            aOff[ks][mr] = r * 64 + ((u ^ (r & 7)) * 8);
        }
        #pragma unroll
        for (int nr = 0; nr < 2; ++nr) {
            const int r = wc * 32 + nr * 16 + l15;
            bOff[ks][nr] = r * 64 + ((u ^ (r & 7)) * 8);
        }
    }

    f32x4 acc[4][2];
    #pragma unroll
    for (int i = 0; i < 4; ++i)
        #pragma unroll
        for (int j = 0; j < 2; ++j) acc[i][j] = (f32x4){0.f, 0.f, 0.f, 0.f};

    // prologue: stage tile 0 into buffer 0
    #pragma unroll
    for (int i = 0; i < 4; ++i) { gload_lds16(aSrc[i], &Asm[0][aDst[i]]); aSrc[i] += BKT; }
    #pragma unroll
    for (int i = 0; i < 2; ++i) { gload_lds16(bSrc[i], &Bsm[0][bDst[i]]); bSrc[i] += BKT; }
    __syncthreads();

    int cur = 0;
    const int NT = NNODES / BKT;   // 128
    for (int t = 0; t < NT; ++t) {
        if (t + 1 < NT) {
            const int nxt = cur ^ 1;
            #pragma unroll
            for (int i = 0; i < 4; ++i) { gload_lds16(aSrc[i], &Asm[nxt][aDst[i]]); aSrc[i] += BKT; }
            #pragma unroll
            for (int i = 0; i < 2; ++i) { gload_lds16(bSrc[i], &Bsm[nxt][bDst[i]]); bSrc[i] += BKT; }
        }
        const unsigned short* Ab = &Asm[cur][0];
        const unsigned short* Bb = &Bsm[cur][0];
        #pragma unroll
        for (int ks = 0; ks < 2; ++ks) {
            bf16x8 av[4], bv[2];
            #pragma unroll
            for (int mr = 0; mr < 4; ++mr) av[mr] = *(const bf16x8*)(Ab + aOff[ks][mr]);
            #pragma unroll
            for (int nr = 0; nr < 2; ++nr) bv[nr] = *(const bf16x8*)(Bb + bOff[ks][nr]);
            #pragma unroll
            for (int mr = 0; mr < 4; ++mr)
                #pragma unroll
                for (int nr = 0; nr < 2; ++nr)
                    acc[mr][nr] = __builtin_amdgcn_mfma_f32_16x16x32_bf16(
                        av[mr], bv[nr], acc[mr][nr], 0, 0, 0);
        }
        __syncthreads();   // drains vmcnt(0) (stage) + lgkm before buffer reuse
        cur ^= 1;
    }

    // epilogue: C/D layout col=lane&15, row=(lane>>4)*4+q
    #pragma unroll
    for (int mr = 0; mr < 4; ++mr) {
        const int grow0 = bm + wr * 64 + mr * 16 + l4 * 4;
        #pragma unroll
        for (int nr = 0; nr < 2; ++nr) {
            const int gcol = bn + wc * 32 + nr * 16 + l15;
            float* cp = C + (size_t)grow0 * 512 + gcol;
            #pragma unroll
            for (int q = 0; q < 4; ++q) cp[(size_t)q * 512] = acc[mr][nr][q];
        }
    }
}

// ============================================================
// Hcat [8192][512] f32 -> Bt [512][8192] bf16 (transpose + convert)
// ============================================================
__global__ __launch_bounds__(256) void gate_hcat_bt(
    const float* __restrict__ Hcat, unsigned short* __restrict__ Bt)
{
    __shared__ float Ts[64][65];
    const int i0 = blockIdx.x * 64;   // Hcat row block
    const int j0 = blockIdx.y * 64;   // Hcat col block
    const int c = threadIdx.x & 63, g = threadIdx.x >> 6;
    #pragma unroll
    for (int ii = 0; ii < 16; ++ii) {
        const int r = g * 16 + ii;
        Ts[r][c] = Hcat[(size_t)(i0 + r) * 512 + j0 + c];
    }
    __syncthreads();
    #pragma unroll
    for (int ii = 0; ii < 16; ++ii) {
        const int r = g * 16 + ii;
        Bt[(size_t)(j0 + r) * NNODES + i0 + c] = f2bf(Ts[c][r]);
    }
}

// ============================================================
// f1 = H @ v00, f2 = H @ v10 : one wave per row
// ============================================================
__global__ __launch_bounds__(256) void gate_f1f2(
    const float* __restrict__ H, const float* __restrict__ v0,
    const float* __restrict__ v1, float* __restrict__ f1, float* __restrict__ f2)
{
    const int wave = threadIdx.x >> 6, lane = threadIdx.x & 63;
    const int row = blockIdx.x * 4 + wave;
    const float4 h = ((const float4*)(H + (size_t)row * DH))[lane];
    const float4 a = ((const float4*)v0)[lane];
    const float4 b = ((const float4*)v1)[lane];
    float s1 = h.x * a.x + h.y * a.y + h.z * a.z + h.w * a.w;
    float s2 = h.x * b.x + h.y * b.y + h.z * b.z + h.w * b.w;
    #pragma unroll
    for (int off = 32; off; off >>= 1) {
        s1 += __shfl_down(s1, off);
        s2 += __shfl_down(s2, off);
    }
    if (lane == 0) { f1[row] = s1; f2[row] = s2; }
}

// ============================================================
// CSR build: histogram, scan, scatter
// ============================================================
__global__ void gate_hist(const int* __restrict__ rows, int* __restrict__ cnt)
{
    const int e = blockIdx.x * 256 + threadIdx.x;
    if (e < NEDGE) atomicAdd(&cnt[rows[e]], 1);
}

__global__ __launch_bounds__(256) void gate_scan(
    const int* __restrict__ cnt, int* __restrict__ rowptr, int* __restrict__ cur)
{
    __shared__ int part[256];
    const int t = threadIdx.x;
    const int base = t * 32;
    int local[32];
    int s = 0;
    #pragma unroll
    for (int i = 0; i < 32; ++i) { local[i] = s; s += cnt[base + i]; }
    part[t] = s;
    __syncthreads();
    for (int d = 1; d < 256; d <<= 1) {
        const int add = (t >= d) ? part[t - d] : 0;
        __syncthreads();
        part[t] += add;
        __syncthreads();
    }
    const int excl = (t == 0) ? 0 : part[t - 1];
    #pragma unroll
    for (int i = 0; i < 32; ++i) {
        const int v = excl + local[i];
        rowptr[base + i] = v;
        cur[base + i] = v;
    }
    if (t == 255) rowptr[NNODES] = excl + s;
}

__global__ void gate_scatter(const int* __restrict__ rows, const int* __restrict__ cols,
                             int* __restrict__ cur, int* __restrict__ col_p)
{
    const int e = blockIdx.x * 256 + threadIdx.x;
    if (e < NEDGE) {
        const int slot = atomicAdd(&cur[rows[e]], 1);
        col_p[slot] = cols[e];
    }
}

// ============================================================
// attention: per-row sigmoid + segment softmax (one wave per row)
// ============================================================
__global__ __launch_bounds__(64) void gate_att(
    const int* __restrict__ rowptr, const int* __restrict__ col_p,
    const float* __restrict__ f1, const float* __restrict__ f2,
    float* __restrict__ att_p)
{
    const int row = blockIdx.x;
    const int s0 = rowptr[row], s1 = rowptr[row + 1];
    const int lane = threadIdx.x;
    const float f1r = f1[row];
    float mx = -1e30f;
    for (int s = s0 + lane; s < s1; s += 64) {
        float u = f1r + f2[col_p[s]];
        u = 1.f / (1.f + expf(-u));
        att_p[s] = u;
        mx = fmaxf(mx, u);
    }
    #pragma unroll
    for (int off = 32; off; off >>= 1) mx = fmaxf(mx, __shfl_xor(mx, off));
    float sum = 0.f;
    for (int s = s0 + lane; s < s1; s += 64) {
        const float ex = expf(att_p[s] - mx);
        att_p[s] = ex;
        sum += ex;
    }
    #pragma unroll
    for (int off = 32; off; off >>= 1) sum += __shfl_xor(sum, off);
    const float inv = 1.f / (sum + 1e-12f);
    for (int s = s0 + lane; s < s1; s += 64) att_p[s] *= inv;
}

// ============================================================
// H_enc[row] = sum att * H[col]
// ============================================================
__global__ __launch_bounds__(256) void gate_spmm_henc(
    const int* __restrict__ rowptr, const int* __restrict__ col_p,
    const float* __restrict__ att_p, const float* __restrict__ H,
    float* __restrict__ Hcat, float* __restrict__ outp, int voff)
{
    const int row = blockIdx.x, d = threadIdx.x;
    const int s0 = rowptr[row], s1 = rowptr[row + 1];
    float acc = 0.f;
    for (int s = s0; s < s1; ++s)
        acc = fmaf(att_p[s], H[(size_t)col_p[s] * DH + d], acc);
    Hcat[(size_t)row * 512 + voff + d] = acc;
    outp[(size_t)row * DH + d] = acc;
}

// ============================================================
// coef write + S_Regular + Cq_loss + bf16(coef) for the MFMA GEMM
// ============================================================
__global__ __launch_bounds__(256) void gate_coef(
    const float* __restrict__ W, const float* __restrict__ Theta,
    float* __restrict__ coef_out, double* __restrict__ accumB,
    unsigned short* __restrict__ wbf)
{
    __shared__ float Ts[64][65];
    __shared__ float red[256];
    const int i0 = blockIdx.x * 64, j0 = blockIdx.y * 64;
    const int t = threadIdx.x;
    const int c = t & 63, rgrp = t >> 6;
    #pragma unroll
    for (int jj = 0; jj < 16; ++jj) {
        const int jr = rgrp * 16 + jj;
        Ts[jr][c] = Theta[(size_t)(j0 + jr) * NNODES + i0 + c];
    }
    __syncthreads();
    float sreg = 0.f, cq = 0.f;
    #pragma unroll
    for (int ii = 0; ii < 16; ++ii) {
        const int rr = rgrp * 16 + ii;
        const int gi = i0 + rr, gj = j0 + c;
        const float w = W[(size_t)gi * NNODES + gj];
        const float cf = (gi == gj) ? 0.f : w;
        coef_out[(size_t)gi * NNODES + gj] = cf;
        if (wbf) wbf[(size_t)gi * NNODES + gj] = f2bf(cf);
        const float a = fabsf(cf);
        sreg += a;
        cq = fmaf(a, fabsf(Ts[c][rr]), cq);
    }
    const int bucket = (blockIdx.x + blockIdx.y) & (NBUCKET - 1);
    red[t] = sreg; __syncthreads();
    for (int d = 128; d; d >>= 1) { if (t < d) red[t] += red[t + d]; __syncthreads(); }
    if (t == 0) atomicAdd(&accumB[bucket * AC_NUM + AC_SREG], (double)red[0]);
    __syncthreads();
    red[t] = cq; __syncthreads();
    for (int d = 128; d; d >>= 1) { if (t < d) red[t] += red[t + d]; __syncthreads(); }
    if (t == 0) atomicAdd(&accumB[bucket * AC_NUM + AC_CQ], (double)red[0]);
}

// ============================================================
// SE: sum((Hcat - HC)^2) over N*512
// ============================================================
__global__ __launch_bounds__(256) void gate_se(
    const float* __restrict__ Hcat, const float* __restrict__ HC,
    double* __restrict__ accumB)
{
    __shared__ float red[256];
    float part = 0.f;
    for (size_t i = (size_t)blockIdx.x * 256 + threadIdx.x;
         i < (size_t)NNODES * 512; i += (size_t)2048 * 256) {
        const float d = Hcat[i] - HC[i];
        part = fmaf(d, d, part);
    }
    const int t = threadIdx.x;
    red[t] = part; __syncthreads();
    for (int d = 128; d; d >>= 1) { if (t < d) red[t] += red[t + d]; __syncthreads(); }
    if (t == 0) atomicAdd(&accumB[(blockIdx.x & (NBUCKET - 1)) * AC_NUM + AC_SE], (double)red[0]);
}

// ============================================================
// consistent: sum((Henc1 - Henc2)^2)
// ============================================================
__global__ __launch_bounds__(256) void gate_cons(
    const float* __restrict__ Hcat, double* __restrict__ accumB)
{
    __shared__ float red[256];
    float part = 0.f;
    for (size_t i = (size_t)blockIdx.x * 256 + threadIdx.x;
         i < (size_t)NNODES * DH; i += (size_t)1024 * 256) {
        const size_t row = i >> 8;
        const int d = (int)(i & 255);
        const float v = Hcat[row * 512 + d] - Hcat[row * 512 + 256 + d];
        part = fmaf(v, v, part);
    }
    const int t = threadIdx.x;
    red[t] = part; __syncthreads();
    for (int d = 128; d; d >>= 1) { if (t < d) red[t] += red[t + d]; __syncthreads(); }
    if (t == 0) atomicAdd(&accumB[(blockIdx.x & (NBUCKET - 1)) * AC_NUM + AC_CONS], (double)red[0]);
}

// ============================================================
// recon + features loss
// ============================================================
__global__ __launch_bounds__(256) void gate_recon_loss(
    const int* __restrict__ rowptr, const int* __restrict__ col_p,
    const float* __restrict__ att_p, const float* __restrict__ Mbuf,
    const float* __restrict__ X, double* __restrict__ accumB)
{
    __shared__ float red[256];
    const int row = blockIdx.x, t = threadIdx.x;
    const int s0 = rowptr[row], s1 = rowptr[row + 1];
    float acc0 = 0.f, acc1 = 0.f, acc2 = 0.f;
    for (int s = s0; s < s1; ++s) {
        const float a = att_p[s];
        const float* mr = Mbuf + (size_t)col_p[s] * MLD;
        acc0 = fmaf(a, mr[t], acc0);
        acc1 = fmaf(a, mr[t + 256], acc1);
        if (t < DIN - 512) acc2 = fmaf(a, mr[t + 512], acc2);
    }
    const float* xr = X + (size_t)row * DIN;
    const float d0 = xr[t] - acc0;
    const float d1 = xr[t + 256] - acc1;
    float part = d0 * d0 + d1 * d1;
    if (t < DIN - 512) { const float d2 = xr[t + 512] - acc2; part = fmaf(d2, d2, part); }
    red[t] = part; __syncthreads();
    for (int d = 128; d; d >>= 1) { if (t < d) red[t] += red[t + d]; __syncthreads(); }
    if (t == 0) atomicAdd(&accumB[(blockIdx.x & (NBUCKET - 1)) * AC_NUM + AC_FEAT], (double)red[0]);
}

// ============================================================
// structure loss
// ============================================================
__global__ __launch_bounds__(256) void gate_struct(
    const int* __restrict__ S, const int* __restrict__ R,
    const float* __restrict__ Hcat, int voff, double* __restrict__ accumB)
{
    __shared__ float red[4];
    const int wave = threadIdx.x >> 6, lane = threadIdx.x & 63;
    const int widx = blockIdx.x * 4 + wave;
    float part = 0.f;
    for (int e = widx; e < NEDGE; e += gridDim.x * 4) {
        const float4 av = ((const float4*)(Hcat + (size_t)S[e] * 512 + voff))[lane];
        const float4 bv = ((const float4*)(Hcat + (size_t)R[e] * 512 + voff))[lane];
        float d = av.x * bv.x + av.y * bv.y + av.z * bv.z + av.w * bv.w;
        #pragma unroll
        for (int off = 32; off; off >>= 1) d += __shfl_xor(d, off);
        if (lane == 0) {
            const float x = d;
            const float sp = (x > 0.f) ? log1pf(expf(-x)) : (-x + log1pf(expf(x)));
            part += sp;
        }
    }
    if (lane == 0) red[wave] = part;
    __syncthreads();
    if (threadIdx.x == 0)
        atomicAdd(&accumB[(blockIdx.x & (NBUCKET - 1)) * AC_NUM + AC_STRUCT],
                  (double)(red[0] + red[1] + red[2] + red[3]));
}

// ============================================================
// z head + cross-entropy
// ============================================================
__global__ __launch_bounds__(256) void gate_zhead(
    const float* __restrict__ tbuf, const float* __restrict__ fczw,
    const float* __restrict__ fczb, const int* __restrict__ p,
    double* __restrict__ accumB)
{
    __shared__ float wz[6 * 512];
    __shared__ float bz[6];
    __shared__ float red[4];
    for (int i = threadIdx.x; i < 6 * 512; i += 256) wz[i] = fczw[i];
    if (threadIdx.x < 6) bz[threadIdx.x] = fczb[threadIdx.x];
    __syncthreads();
    const int wave = threadIdx.x >> 6, lane = threadIdx.x & 63;
    const int row = blockIdx.x * 4 + wave;
    const float* tr = tbuf + (size_t)row * 512;
    float part[6] = {};
    for (int j = lane; j < 512; j += 64) {
        const float tv = tr[j];
        #pragma unroll
        for (int c = 0; c < 6; ++c) part[c] = fmaf(tv, wz[c * 512 + j], part[c]);
    }
    #pragma unroll
    for (int c = 0; c < 6; ++c)
        #pragma unroll
        for (int off = 32; off; off >>= 1) part[c] += __shfl_xor(part[c], off);
    if (lane == 0) {
        float z[6], mx = -1e30f;
        #pragma unroll
        for (int c = 0; c < 6; ++c) { z[c] = part[c] + bz[c]; mx = fmaxf(mx, z[c]); }
        float se = 0.f;
        #pragma unroll
        for (int c = 0; c < 6; ++c) se += expf(z[c] - mx);
        const float lse = mx + logf(se);
        red[wave] = lse - z[p[row]];
    }
    __syncthreads();
    if (threadIdx.x == 0)
        atomicAdd(&accumB[(blockIdx.x & (NBUCKET - 1)) * AC_NUM + AC_DENSE],
                  (double)(red[0] + red[1] + red[2] + red[3]));
}

// ============================================================
// final: sum buckets, combine, write scalar outputs
// ============================================================
__global__ void gate_final(const double* __restrict__ accumB, float* __restrict__ out)
{
    if (threadIdx.x == 0 && blockIdx.x == 0) {
        double acc[AC_NUM];
        for (int i = 0; i < AC_NUM; ++i) acc[i] = 0.0;
        for (int b = 0; b < NBUCKET; ++b)
            for (int i = 0; i < AC_NUM; ++i) acc[i] += accumB[b * AC_NUM + i];
        const double feat = acc[AC_FEAT], st = acc[AC_STRUCT];
        const double se = 0.5 * acc[AC_SE];
        const double cons = acc[AC_CONS], sreg = acc[AC_SREG];
        const double cq = acc[AC_CQ], dl = acc[AC_DENSE];
        const double pre = feat + st + 10.0 * se + 0.01 * cons + sreg;
        const double loss = 0.01 * feat + st + 10.0 * se + 0.001 * cons + sreg
                          + 5.0 * cq + 5.0 * dl;
        out[0] = (float)pre;
        out[1] = (float)loss;
        out[2] = (float)dl;
        out[3] = (float)feat;
        out[4] = (float)st;
        out[5] = (float)se;
        out[OFF_CONS] = (float)cons;
        out[OFF_SREG] = (float)sreg;
        out[OFF_CQ]   = (float)cq;
    }
}

// ============================================================
extern "C" void kernel_launch(void* const* d_in, const int* in_sizes, int n_in,
                              void* d_out, int out_size, void* d_ws, size_t ws_size,
                              hipStream_t stream)
{
    (void)in_sizes; (void)n_in; (void)out_size;
    const float* X      = (const float*)d_in[0];
    const float* X2     = (const float*)d_in[1];
    const float* Theta  = (const float*)d_in[2];
    const int*   Aidx   = (const int*)d_in[3];
    const int*   A2idx  = (const int*)d_in[5];
    const int*   S      = (const int*)d_in[7];
    const int*   R      = (const int*)d_in[8];
    const int*   S2     = (const int*)d_in[9];
    const int*   R2     = (const int*)d_in[10];
    const int*   p      = (const int*)d_in[11];
    const float* W0     = (const float*)d_in[13];
    const float* v00    = (const float*)d_in[14];
    const float* v10    = (const float*)d_in[15];
    const float* weight = (const float*)d_in[16];
    const float* fc1_w  = (const float*)d_in[17];
    const float* fc1_b  = (const float*)d_in[18];
    const float* fcz_w  = (const float*)d_in[19];
    const float* fcz_b  = (const float*)d_in[20];
    const float* fc2_w  = (const float*)d_in[21];
    const float* fc2_b  = (const float*)d_in[22];
    const float* fcz2_w = (const float*)d_in[23];
    const float* fcz2_b = (const float*)d_in[24];
    float* out = (float*)d_out;

    // ---- workspace carve ----
    char* wp = (char*)d_ws;
    auto alloc = [&](size_t bytes) -> void* {
        void* r = (void*)wp;
        wp += (bytes + 255) & ~(size_t)255;
        return r;
    };
    float* H1    = (float*)alloc((size_t)NNODES * DH * 4);
    float* H2    = (float*)alloc((size_t)NNODES * DH * 4);
    float* Hcat  = (float*)alloc((size_t)NNODES * 512 * 4);
    float* HCcat = (float*)alloc((size_t)NNODES * 512 * 4);
    float* Mbuf  = (float*)alloc((size_t)NNODES * MLD * 4);  // also reused as tbuf
    float* tbuf  = Mbuf;
    float* f1a = (float*)alloc(NNODES * 4);
    float* f2a = (float*)alloc(NNODES * 4);
    float* f1b = (float*)alloc(NNODES * 4);
    float* f2b = (float*)alloc(NNODES * 4);
    int* cnt    = (int*)alloc(2 * NNODES * 4);
    int* rowptr = (int*)alloc(2 * (NNODES + 1) * 4);
    int* cur    = (int*)alloc(2 * NNODES * 4);
    int* colp   = (int*)alloc(2 * (size_t)NEDGE * 4);
    float* attp = (float*)alloc(2 * (size_t)NEDGE * 4);
    double* accumB = (double*)alloc(NBUCKET * AC_NUM * 8);
    // MFMA-path scratch (large): bf16 coef matrix + transposed bf16 Hcat
    unsigned short* Wbf = (unsigned short*)alloc((size_t)NNODES * NNODES * 2);
    unsigned short* Bt  = (unsigned short*)alloc((size_t)512 * NNODES * 2);
    const bool use_mfma = ((size_t)(wp - (char*)d_ws) <= ws_size);

    hipMemsetAsync(cnt, 0, 2 * NNODES * 4, stream);
    hipMemsetAsync(accumB, 0, NBUCKET * AC_NUM * 8, stream);

    // encode: H = X @ W0 (both views)
    gate_gemm_nn<<<dim3(NNODES / 64, DH / 64), 256, 0, stream>>>(
        X, W0, H1, NNODES, DH, DIN, DIN, DH, DH);
    gate_gemm_nn<<<dim3(NNODES / 64, DH / 64), 256, 0, stream>>>(
        X2, W0, H2, NNODES, DH, DIN, DIN, DH, DH);
    gate_f1f2<<<NNODES / 4, 256, 0, stream>>>(H1, v00, v10, f1a, f2a);
    gate_f1f2<<<NNODES / 4, 256, 0, stream>>>(H2, v00, v10, f1b, f2b);

    // CSR build
    gate_hist<<<NEDGE / 256, 256, 0, stream>>>(Aidx, cnt);
    gate_hist<<<NEDGE / 256, 256, 0, stream>>>(A2idx, cnt + NNODES);
    gate_scan<<<1, 256, 0, stream>>>(cnt, rowptr, cur);
    gate_scan<<<1, 256, 0, stream>>>(cnt + NNODES, rowptr + NNODES + 1, cur + NNODES);
    gate_scatter<<<NEDGE / 256, 256, 0, stream>>>(Aidx, Aidx + NEDGE, cur, colp);
    gate_scatter<<<NEDGE / 256, 256, 0, stream>>>(A2idx, A2idx + NEDGE, cur + NNODES, colp + NEDGE);

    // attention + aggregation
    gate_att<<<NNODES, 64, 0, stream>>>(rowptr, colp, f1a, f2a, attp);
    gate_att<<<NNODES, 64, 0, stream>>>(rowptr + NNODES + 1, colp + NEDGE, f1b, f2b, attp + NEDGE);
    gate_spmm_henc<<<NNODES, 256, 0, stream>>>(rowptr, colp, attp, H1, Hcat, out + OFF_H1, 0);
    gate_spmm_henc<<<NNODES, 256, 0, stream>>>(rowptr + NNODES + 1, colp + NEDGE, attp + NEDGE,
                                               H2, Hcat, out + OFF_H2, 256);

    // coef write + S_Regular + Cq (+ bf16 coef for MFMA path)
    gate_coef<<<dim3(NNODES / 64, NNODES / 64), 256, 0, stream>>>(
        weight, Theta, out + OFF_COEF, accumB, use_mfma ? Wbf : nullptr);

    // HC = coef @ [Henc1 | Henc2]
    if (use_mfma) {
        gate_hcat_bt<<<dim3(NNODES / 64, 512 / 64), 256, 0, stream>>>(Hcat, Bt);
        gate_gemm_coef_mfma<<<dim3(NNODES / BMT, 512 / BNT), 256, 0, stream>>>(Wbf, Bt, HCcat);
    } else {
        gate_gemm_coef<<<dim3(NNODES / 128, 512 / 64), 256, 0, stream>>>(weight, Hcat, HCcat);
    }

    gate_se<<<2048, 256, 0, stream>>>(Hcat, HCcat, accumB);
    gate_cons<<<1024, 256, 0, stream>>>(Hcat, accumB);

    // view 1: M = HC1 @ W0^T ; features loss
    gate_gemm_bt<<<dim3(NNODES / 64, (DIN + 63) / 64), 256, 0, stream>>>(
        HCcat, 512, W0, nullptr, Mbuf, MLD, NNODES, DIN, DH);
    gate_recon_loss<<<NNODES, 256, 0, stream>>>(rowptr, colp, attp, Mbuf, X, accumB);
    // view 2
    gate_gemm_bt<<<dim3(NNODES / 64, (DIN + 63) / 64), 256, 0, stream>>>(
        HCcat + 256, 512, W0, nullptr, Mbuf, MLD, NNODES, DIN, DH);
    gate_recon_loss<<<NNODES, 256, 0, stream>>>(rowptr + NNODES + 1, colp + NEDGE,
                                                attp + NEDGE, Mbuf, X2, accumB);

    // dense heads
    gate_gemm_bt<<<dim3(NNODES / 64, FCDIM / 64), 256, 0, stream>>>(
        Hcat, 512, fc1_w, fc1_b, tbuf, 512, NNODES, FCDIM, DH);
    gate_zhead<<<NNODES / 4, 256, 0, stream>>>(tbuf, fcz_w, fcz_b, p, accumB);
    gate_gemm_bt<<<dim3(NNODES / 64, FCDIM / 64), 256, 0, stream>>>(
        Hcat + 256, 512, fc2_w, fc2_b, tbuf, 512, NNODES, FCDIM, DH);
    gate_zhead<<<NNODES / 4, 256, 0, stream>>>(tbuf, fcz2_w, fcz2_b, p, accumB);

    // structure losses
    gate_struct<<<2048, 256, 0, stream>>>(S, R, Hcat, 0, accumB);
    gate_struct<<<2048, 256, 0, stream>>>(S2, R2, Hcat, 256, accumB);

    gate_final<<<1, 64, 0, stream>>>(accumB, out);
}

// Round 3
// 1678.325 us; speedup vs baseline: 1.5636x; 1.0839x over previous
//
#include <hip/hip_runtime.h>
#include <math.h>

#define NNODES 8192
#define DIN 561
#define DH 256
#define NEDGE 262144

enum { AC_FEAT = 0, AC_STRUCT, AC_SE, AC_CONS, AC_SREG, AC_CQ, AC_DENSE, AC_NUM };
#define NBUCKET 64

// ---- output offsets (floats) ----
#define OFF_COEF ((size_t)6)
#define OFF_CONS ((size_t)6 + (size_t)NNODES * NNODES)
#define OFF_SREG (OFF_CONS + 1)
#define OFF_CQ   (OFF_CONS + 2)
#define OFF_H1   (OFF_CONS + 3)
#define OFF_H2   (OFF_H1 + (size_t)NNODES * DH)

typedef short bf16x8 __attribute__((ext_vector_type(8)));
typedef float f32x4  __attribute__((ext_vector_type(4)));

__device__ __forceinline__ unsigned short f2bf(float f) {
    union { float f; unsigned int u; } v; v.f = f;
    const unsigned int u = v.u;
    return (unsigned short)((u + 0x7fffu + ((u >> 16) & 1u)) >> 16);  // RNE
}
__device__ __forceinline__ float bf2f(unsigned short u) {
    union { unsigned int u; float f; } v; v.u = ((unsigned int)u) << 16;
    return v.f;
}

__device__ __forceinline__ void gload_lds16(const void* g, void* l) {
    __builtin_amdgcn_global_load_lds(
        (const __attribute__((address_space(1))) unsigned int*)g,
        (__attribute__((address_space(3))) unsigned int*)l, 16, 0, 0);
}

// ============================================================
// GEMM NN: C[MxNn] = A[MxK] @ B[KxNn]  (fp32; used for H = X @ W0)
// ============================================================
__global__ __launch_bounds__(256) void gate_gemm_nn(
    const float* __restrict__ A, const float* __restrict__ B,
    float* __restrict__ C, int M, int Nn, int K, int lda, int ldb, int ldc)
{
    __shared__ float As[32][68];
    __shared__ float Bs[32][68];
    const int bm = blockIdx.x * 64, bn = blockIdx.y * 64;
    const int tid = threadIdx.x;
    const int tx = tid & 15, ty = tid >> 4;
    float acc[4][4] = {};
    for (int k0 = 0; k0 < K; k0 += 32) {
        const int ar = tid >> 2, ak = (tid & 3) * 8;
        #pragma unroll
        for (int j = 0; j < 8; ++j) {
            const int gk = k0 + ak + j;
            As[ak + j][ar] = (gk < K) ? A[(size_t)(bm + ar) * lda + gk] : 0.f;
        }
        const int bk = tid >> 3, bn0 = (tid & 7) * 8;
        const int gk = k0 + bk;
        #pragma unroll
        for (int j = 0; j < 8; ++j) {
            const int gn = bn + bn0 + j;
            Bs[bk][bn0 + j] = (gk < K && gn < Nn) ? B[(size_t)gk * ldb + gn] : 0.f;
        }
        __syncthreads();
        #pragma unroll
        for (int k = 0; k < 32; ++k) {
            float a[4], b[4];
            #pragma unroll
            for (int i = 0; i < 4; ++i) a[i] = As[k][ty * 4 + i];
            #pragma unroll
            for (int j = 0; j < 4; ++j) b[j] = Bs[k][tx * 4 + j];
            #pragma unroll
            for (int i = 0; i < 4; ++i)
                #pragma unroll
                for (int j = 0; j < 4; ++j) acc[i][j] = fmaf(a[i], b[j], acc[i][j]);
        }
        __syncthreads();
    }
    #pragma unroll
    for (int i = 0; i < 4; ++i) {
        const int gm = bm + ty * 4 + i;
        if (gm >= M) continue;
        #pragma unroll
        for (int j = 0; j < 4; ++j) {
            const int gn = bn + tx * 4 + j;
            if (gn < Nn) C[(size_t)gm * ldc + gn] = acc[i][j];
        }
    }
}

// ============================================================
// fp32 fallback: HC = (W - diag) @ Hcat
// ============================================================
__global__ __launch_bounds__(256) void gate_gemm_coef(
    const float* __restrict__ W, const float* __restrict__ B, float* __restrict__ C)
{
    __shared__ float As[16][132];
    __shared__ float Bs[16][64];
    const int bm = blockIdx.x * 128, bn = blockIdx.y * 64;
    const int tid = threadIdx.x;
    const int tx = tid & 15, ty = tid >> 4;
    float acc[8][4] = {};
    for (int k0 = 0; k0 < NNODES; k0 += 16) {
        const int ar = tid >> 1, ak = (tid & 1) * 8;
        const float* Ap = W + (size_t)(bm + ar) * NNODES + k0 + ak;
        const bool maskdiag = (k0 + 15 >= bm) && (k0 <= bm + 127);
        if (maskdiag) {
            #pragma unroll
            for (int j = 0; j < 8; ++j) {
                float v = Ap[j];
                if (bm + ar == k0 + ak + j) v = 0.f;
                As[ak + j][ar] = v;
            }
        } else {
            const float4 v0 = *(const float4*)(Ap);
            const float4 v1 = *(const float4*)(Ap + 4);
            As[ak + 0][ar] = v0.x; As[ak + 1][ar] = v0.y;
            As[ak + 2][ar] = v0.z; As[ak + 3][ar] = v0.w;
            As[ak + 4][ar] = v1.x; As[ak + 5][ar] = v1.y;
            As[ak + 6][ar] = v1.z; As[ak + 7][ar] = v1.w;
        }
        const int bk = tid >> 4, bn0 = (tid & 15) * 4;
        *(float4*)&Bs[bk][bn0] = *(const float4*)(B + (size_t)(k0 + bk) * 512 + bn + bn0);
        __syncthreads();
        #pragma unroll
        for (int k = 0; k < 16; ++k) {
            float a[8], b[4];
            #pragma unroll
            for (int i = 0; i < 8; ++i) a[i] = As[k][ty * 8 + i];
            #pragma unroll
            for (int j = 0; j < 4; ++j) b[j] = Bs[k][tx * 4 + j];
            #pragma unroll
            for (int i = 0; i < 8; ++i)
                #pragma unroll
                for (int j = 0; j < 4; ++j) acc[i][j] = fmaf(a[i], b[j], acc[i][j]);
        }
        __syncthreads();
    }
    #pragma unroll
    for (int i = 0; i < 8; ++i) {
        float4 v = make_float4(acc[i][0], acc[i][1], acc[i][2], acc[i][3]);
        *(float4*)(C + (size_t)(bm + ty * 8 + i) * 512 + bn + tx * 4) = v;
    }
}

// ============================================================
// MFMA GEMM: HC[8192x512] = Wbf(diag-zeroed bf16) @ Bt^T
// 128x64 tile, BK=64, 4 waves (2x2), double-buffered LDS, XOR-swizzled.
// ============================================================
#define BMT 128
#define BNT 64
#define BKT 64

__global__ __launch_bounds__(256, 2) void gate_gemm_coef_mfma(
    const unsigned short* __restrict__ Wbf,
    const unsigned short* __restrict__ Bt,
    float* __restrict__ C)
{
    __shared__ __align__(16) unsigned short Asm[2][BMT * BKT];
    __shared__ __align__(16) unsigned short Bsm[2][BNT * BKT];
    const int tid = threadIdx.x;
    const int wid = tid >> 6, lane = tid & 63;
    const int bm = blockIdx.x * BMT, bn = blockIdx.y * BNT;
    const int wr = wid >> 1, wc = wid & 1;

    const int l3 = lane >> 3, l7 = lane & 7;
    const int kxor = (l7 ^ l3) * 8;
    const unsigned short* aSrc[4];
    int aDst[4];
    #pragma unroll
    for (int i = 0; i < 4; ++i) {
        const int c = wid + i * 4;
        const int r = c * 8 + l3;
        aSrc[i] = Wbf + (size_t)(bm + r) * NNODES + kxor;
        aDst[i] = c * 512;
    }
    const unsigned short* bSrc[2];
    int bDst[2];
    #pragma unroll
    for (int i = 0; i < 2; ++i) {
        const int c = wid + i * 4;
        const int r = c * 8 + l3;
        bSrc[i] = Bt + (size_t)(bn + r) * NNODES + kxor;
        bDst[i] = c * 512;
    }

    const int l15 = lane & 15, l4 = lane >> 4;
    int aOff[2][4], bOff[2][2];
    #pragma unroll
    for (int ks = 0; ks < 2; ++ks) {
        const int u = ks * 4 + l4;
        #pragma unroll
        for (int mr = 0; mr < 4; ++mr) {
            const int r = wr * 64 + mr * 16 + l15;
            aOff[ks][mr] = r * 64 + ((u ^ (r & 7)) * 8);
        }
        #pragma unroll
        for (int nr = 0; nr < 2; ++nr) {
            const int r = wc * 32 + nr * 16 + l15;
            bOff[ks][nr] = r * 64 + ((u ^ (r & 7)) * 8);
        }
    }

    f32x4 acc[4][2];
    #pragma unroll
    for (int i = 0; i < 4; ++i)
        #pragma unroll
        for (int j = 0; j < 2; ++j) acc[i][j] = (f32x4){0.f, 0.f, 0.f, 0.f};

    #pragma unroll
    for (int i = 0; i < 4; ++i) { gload_lds16(aSrc[i], &Asm[0][aDst[i]]); aSrc[i] += BKT; }
    #pragma unroll
    for (int i = 0; i < 2; ++i) { gload_lds16(bSrc[i], &Bsm[0][bDst[i]]); bSrc[i] += BKT; }
    __syncthreads();

    int cur = 0;
    const int NT = NNODES / BKT;
    for (int t = 0; t < NT; ++t) {
        if (t + 1 < NT) {
            const int nxt = cur ^ 1;
            #pragma unroll
            for (int i = 0; i < 4; ++i) { gload_lds16(aSrc[i], &Asm[nxt][aDst[i]]); aSrc[i] += BKT; }
            #pragma unroll
            for (int i = 0; i < 2; ++i) { gload_lds16(bSrc[i], &Bsm[nxt][bDst[i]]); bSrc[i] += BKT; }
        }
        const unsigned short* Ab = &Asm[cur][0];
        const unsigned short* Bb = &Bsm[cur][0];
        #pragma unroll
        for (int ks = 0; ks < 2; ++ks) {
            bf16x8 av[4], bv[2];
            #pragma unroll
            for (int mr = 0; mr < 4; ++mr) av[mr] = *(const bf16x8*)(Ab + aOff[ks][mr]);
            #pragma unroll
            for (int nr = 0; nr < 2; ++nr) bv[nr] = *(const bf16x8*)(Bb + bOff[ks][nr]);
            #pragma unroll
            for (int mr = 0; mr < 4; ++mr)
                #pragma unroll
                for (int nr = 0; nr < 2; ++nr)
                    acc[mr][nr] = __builtin_amdgcn_mfma_f32_16x16x32_bf16(
                        av[mr], bv[nr], acc[mr][nr], 0, 0, 0);
        }
        __syncthreads();
        cur ^= 1;
    }

    #pragma unroll
    for (int mr = 0; mr < 4; ++mr) {
        const int grow0 = bm + wr * 64 + mr * 16 + l4 * 4;
        #pragma unroll
        for (int nr = 0; nr < 2; ++nr) {
            const int gcol = bn + wc * 32 + nr * 16 + l15;
            float* cp = C + (size_t)grow0 * 512 + gcol;
            #pragma unroll
            for (int q = 0; q < 4; ++q) cp[(size_t)q * 512] = acc[mr][nr][q];
        }
    }
}

// ============================================================
// MFMA recon GEMM + fused features loss:
//   Xr[8192x576] = PHCbf[8192x256] @ w0bf[576x256]^T ; feat += (X - Xr)^2
// K=256 (NT=4). Xr never materialized.
// ============================================================
__global__ __launch_bounds__(256, 2) void gate_mfma_recon(
    const unsigned short* __restrict__ Abf,
    const unsigned short* __restrict__ Bbf,
    const float* __restrict__ X,
    double* __restrict__ accumB)
{
    __shared__ __align__(16) unsigned short Asm[2][BMT * BKT];
    __shared__ __align__(16) unsigned short Bsm[2][BNT * BKT];
    __shared__ float red[256];
    const int tid = threadIdx.x;
    const int wid = tid >> 6, lane = tid & 63;
    const int bm = blockIdx.x * BMT, bn = blockIdx.y * BNT;
    const int wr = wid >> 1, wc = wid & 1;

    const int l3 = lane >> 3, l7 = lane & 7;
    const int kxor = (l7 ^ l3) * 8;
    const unsigned short* aSrc[4];
    int aDst[4];
    #pragma unroll
    for (int i = 0; i < 4; ++i) {
        const int c = wid + i * 4;
        const int r = c * 8 + l3;
        aSrc[i] = Abf + (size_t)(bm + r) * DH + kxor;
        aDst[i] = c * 512;
    }
    const unsigned short* bSrc[2];
    int bDst[2];
    #pragma unroll
    for (int i = 0; i < 2; ++i) {
        const int c = wid + i * 4;
        const int r = c * 8 + l3;
        bSrc[i] = Bbf + (size_t)(bn + r) * DH + kxor;
        bDst[i] = c * 512;
    }

    const int l15 = lane & 15, l4 = lane >> 4;
    int aOff[2][4], bOff[2][2];
    #pragma unroll
    for (int ks = 0; ks < 2; ++ks) {
        const int u = ks * 4 + l4;
        #pragma unroll
        for (int mr = 0; mr < 4; ++mr) {
            const int r = wr * 64 + mr * 16 + l15;
            aOff[ks][mr] = r * 64 + ((u ^ (r & 7)) * 8);
        }
        #pragma unroll
        for (int nr = 0; nr < 2; ++nr) {
            const int r = wc * 32 + nr * 16 + l15;
            bOff[ks][nr] = r * 64 + ((u ^ (r & 7)) * 8);
        }
    }

    f32x4 acc[4][2];
    #pragma unroll
    for (int i = 0; i < 4; ++i)
        #pragma unroll
        for (int j = 0; j < 2; ++j) acc[i][j] = (f32x4){0.f, 0.f, 0.f, 0.f};

    #pragma unroll
    for (int i = 0; i < 4; ++i) { gload_lds16(aSrc[i], &Asm[0][aDst[i]]); aSrc[i] += BKT; }
    #pragma unroll
    for (int i = 0; i < 2; ++i) { gload_lds16(bSrc[i], &Bsm[0][bDst[i]]); bSrc[i] += BKT; }
    __syncthreads();

    int cur = 0;
    const int NT = DH / BKT;   // 4
    for (int t = 0; t < NT; ++t) {
        if (t + 1 < NT) {
            const int nxt = cur ^ 1;
            #pragma unroll
            for (int i = 0; i < 4; ++i) { gload_lds16(aSrc[i], &Asm[nxt][aDst[i]]); aSrc[i] += BKT; }
            #pragma unroll
            for (int i = 0; i < 2; ++i) { gload_lds16(bSrc[i], &Bsm[nxt][bDst[i]]); bSrc[i] += BKT; }
        }
        const unsigned short* Ab = &Asm[cur][0];
        const unsigned short* Bb = &Bsm[cur][0];
        #pragma unroll
        for (int ks = 0; ks < 2; ++ks) {
            bf16x8 av[4], bv[2];
            #pragma unroll
            for (int mr = 0; mr < 4; ++mr) av[mr] = *(const bf16x8*)(Ab + aOff[ks][mr]);
            #pragma unroll
            for (int nr = 0; nr < 2; ++nr) bv[nr] = *(const bf16x8*)(Bb + bOff[ks][nr]);
            #pragma unroll
            for (int mr = 0; mr < 4; ++mr)
                #pragma unroll
                for (int nr = 0; nr < 2; ++nr)
                    acc[mr][nr] = __builtin_amdgcn_mfma_f32_16x16x32_bf16(
                        av[mr], bv[nr], acc[mr][nr], 0, 0, 0);
        }
        __syncthreads();
        cur ^= 1;
    }

    // fused loss epilogue: part += (X - Xr)^2 over valid cols
    float part = 0.f;
    #pragma unroll
    for (int mr = 0; mr < 4; ++mr) {
        const int grow0 = bm + wr * 64 + mr * 16 + l4 * 4;
        #pragma unroll
        for (int nr = 0; nr < 2; ++nr) {
            const int gcol = bn + wc * 32 + nr * 16 + l15;
            if (gcol < DIN) {
                const float* xp = X + (size_t)grow0 * DIN + gcol;
                #pragma unroll
                for (int q = 0; q < 4; ++q) {
                    const float d = xp[(size_t)q * DIN] - acc[mr][nr][q];
                    part = fmaf(d, d, part);
                }
            }
        }
    }
    red[tid] = part; __syncthreads();
    for (int d = 128; d; d >>= 1) { if (tid < d) red[tid] += red[tid + d]; __syncthreads(); }
    if (tid == 0)
        atomicAdd(&accumB[((blockIdx.x + blockIdx.y) & (NBUCKET - 1)) * AC_NUM + AC_FEAT],
                  (double)red[0]);
}

// ============================================================
// Hcat [8192][512] f32 -> Bt [512][8192] bf16 (transpose + convert)
// ============================================================
__global__ __launch_bounds__(256) void gate_hcat_bt(
    const float* __restrict__ Hcat, unsigned short* __restrict__ Bt)
{
    __shared__ float Ts[64][65];
    const int i0 = blockIdx.x * 64;
    const int j0 = blockIdx.y * 64;
    const int c = threadIdx.x & 63, g = threadIdx.x >> 6;
    #pragma unroll
    for (int ii = 0; ii < 16; ++ii) {
        const int r = g * 16 + ii;
        Ts[r][c] = Hcat[(size_t)(i0 + r) * 512 + j0 + c];
    }
    __syncthreads();
    #pragma unroll
    for (int ii = 0; ii < 16; ++ii) {
        const int r = g * 16 + ii;
        Bt[(size_t)(j0 + r) * NNODES + i0 + c] = f2bf(Ts[c][r]);
    }
}

// ============================================================
// W0 [561][256] f32 -> w0bf [576][256] bf16 (zero-padded rows)
// ============================================================
__global__ __launch_bounds__(256) void gate_w0bf(
    const float* __restrict__ W0, unsigned short* __restrict__ w0bf)
{
    const int idx = blockIdx.x * 256 + threadIdx.x;
    const int n = idx >> 8;
    w0bf[idx] = (n < DIN) ? f2bf(W0[idx]) : (unsigned short)0;
}

// ============================================================
// fold z-head: zw[c][k] = sum_j fczw[c][j] * fc1w[j][k]; zb[c]=fczb[c]+sum fczw*b1
// blockIdx.x selects view. zw buffer: 6*256 + 8 floats.
// ============================================================
__global__ __launch_bounds__(256) void gate_zfold(
    const float* __restrict__ fc1w_1, const float* __restrict__ fc1b_1,
    const float* __restrict__ fczw_1, const float* __restrict__ fczb_1,
    const float* __restrict__ fc1w_2, const float* __restrict__ fc1b_2,
    const float* __restrict__ fczw_2, const float* __restrict__ fczb_2,
    float* __restrict__ zw1, float* __restrict__ zw2)
{
    const float* fc1w = blockIdx.x ? fc1w_2 : fc1w_1;
    const float* fc1b = blockIdx.x ? fc1b_2 : fc1b_1;
    const float* fczw = blockIdx.x ? fczw_2 : fczw_1;
    const float* fczb = blockIdx.x ? fczb_2 : fczb_1;
    float* zw = blockIdx.x ? zw2 : zw1;
    __shared__ float wcz[6 * 512];
    __shared__ float b1s[512];
    const int t = threadIdx.x;
    for (int i = t; i < 6 * 512; i += 256) wcz[i] = fczw[i];
    for (int i = t; i < 512; i += 256) b1s[i] = fc1b[i];
    __syncthreads();
    float acc[6] = {};
    for (int j = 0; j < 512; ++j) {
        const float w = fc1w[(size_t)j * DH + t];
        #pragma unroll
        for (int c = 0; c < 6; ++c) acc[c] = fmaf(wcz[c * 512 + j], w, acc[c]);
    }
    #pragma unroll
    for (int c = 0; c < 6; ++c) zw[c * DH + t] = acc[c];
    if (t < 6) {
        float s = fczb[t];
        for (int j = 0; j < 512; ++j) s = fmaf(wcz[t * 512 + j], b1s[j], s);
        zw[6 * DH + t] = s;
    }
}

// ============================================================
// z head (folded) + cross-entropy: wave per row, reads Henc directly
// ============================================================
__global__ __launch_bounds__(256) void gate_zhead2(
    const float* __restrict__ Hcat, int voff, const float* __restrict__ zwb,
    const int* __restrict__ p, double* __restrict__ accumB)
{
    __shared__ float zw[6 * DH];
    __shared__ float zb[6];
    __shared__ float red[4];
    const int t = threadIdx.x;
    for (int i = t; i < 6 * DH; i += 256) zw[i] = zwb[i];
    if (t < 6) zb[t] = zwb[6 * DH + t];
    __syncthreads();
    const int wave = t >> 6, lane = t & 63;
    const int row = blockIdx.x * 4 + wave;
    const float4 h = ((const float4*)(Hcat + (size_t)row * 512 + voff))[lane];
    float part[6];
    #pragma unroll
    for (int c = 0; c < 6; ++c) {
        const float4 w = *(const float4*)&zw[c * DH + lane * 4];
        part[c] = h.x * w.x + h.y * w.y + h.z * w.z + h.w * w.w;
    }
    #pragma unroll
    for (int c = 0; c < 6; ++c)
        #pragma unroll
        for (int off = 32; off; off >>= 1) part[c] += __shfl_xor(part[c], off);
    if (lane == 0) {
        float z[6], mx = -1e30f;
        #pragma unroll
        for (int c = 0; c < 6; ++c) { z[c] = part[c] + zb[c]; mx = fmaxf(mx, z[c]); }
        float se = 0.f;
        #pragma unroll
        for (int c = 0; c < 6; ++c) se += expf(z[c] - mx);
        const float lse = mx + logf(se);
        red[wave] = lse - z[p[row]];
    }
    __syncthreads();
    if (t == 0)
        atomicAdd(&accumB[(blockIdx.x & (NBUCKET - 1)) * AC_NUM + AC_DENSE],
                  (double)(red[0] + red[1] + red[2] + red[3]));
}

// ============================================================
// f1 = H @ v00, f2 = H @ v10 : one wave per row
// ============================================================
__global__ __launch_bounds__(256) void gate_f1f2(
    const float* __restrict__ H, const float* __restrict__ v0,
    const float* __restrict__ v1, float* __restrict__ f1, float* __restrict__ f2)
{
    const int wave = threadIdx.x >> 6, lane = threadIdx.x & 63;
    const int row = blockIdx.x * 4 + wave;
    const float4 h = ((const float4*)(H + (size_t)row * DH))[lane];
    const float4 a = ((const float4*)v0)[lane];
    const float4 b = ((const float4*)v1)[lane];
    float s1 = h.x * a.x + h.y * a.y + h.z * a.z + h.w * a.w;
    float s2 = h.x * b.x + h.y * b.y + h.z * b.z + h.w * b.w;
    #pragma unroll
    for (int off = 32; off; off >>= 1) {
        s1 += __shfl_down(s1, off);
        s2 += __shfl_down(s2, off);
    }
    if (lane == 0) { f1[row] = s1; f2[row] = s2; }
}

// ============================================================
// CSR build: histogram, scan, scatter
// ============================================================
__global__ void gate_hist(const int* __restrict__ rows, int* __restrict__ cnt)
{
    const int e = blockIdx.x * 256 + threadIdx.x;
    if (e < NEDGE) atomicAdd(&cnt[rows[e]], 1);
}

__global__ __launch_bounds__(256) void gate_scan(
    const int* __restrict__ cnt, int* __restrict__ rowptr, int* __restrict__ cur)
{
    __shared__ int part[256];
    const int t = threadIdx.x;
    const int base = t * 32;
    int local[32];
    int s = 0;
    #pragma unroll
    for (int i = 0; i < 32; ++i) { local[i] = s; s += cnt[base + i]; }
    part[t] = s;
    __syncthreads();
    for (int d = 1; d < 256; d <<= 1) {
        const int add = (t >= d) ? part[t - d] : 0;
        __syncthreads();
        part[t] += add;
        __syncthreads();
    }
    const int excl = (t == 0) ? 0 : part[t - 1];
    #pragma unroll
    for (int i = 0; i < 32; ++i) {
        const int v = excl + local[i];
        rowptr[base + i] = v;
        cur[base + i] = v;
    }
    if (t == 255) rowptr[NNODES] = excl + s;
}

__global__ void gate_scatter(const int* __restrict__ rows, const int* __restrict__ cols,
                             int* __restrict__ cur, int* __restrict__ col_p)
{
    const int e = blockIdx.x * 256 + threadIdx.x;
    if (e < NEDGE) {
        const int slot = atomicAdd(&cur[rows[e]], 1);
        col_p[slot] = cols[e];
    }
}

// ============================================================
// attention: per-row sigmoid + segment softmax (one wave per row)
// ============================================================
__global__ __launch_bounds__(64) void gate_att(
    const int* __restrict__ rowptr, const int* __restrict__ col_p,
    const float* __restrict__ f1, const float* __restrict__ f2,
    float* __restrict__ att_p)
{
    const int row = blockIdx.x;
    const int s0 = rowptr[row], s1 = rowptr[row + 1];
    const int lane = threadIdx.x;
    const float f1r = f1[row];
    float mx = -1e30f;
    for (int s = s0 + lane; s < s1; s += 64) {
        float u = f1r + f2[col_p[s]];
        u = 1.f / (1.f + expf(-u));
        att_p[s] = u;
        mx = fmaxf(mx, u);
    }
    #pragma unroll
    for (int off = 32; off; off >>= 1) mx = fmaxf(mx, __shfl_xor(mx, off));
    float sum = 0.f;
    for (int s = s0 + lane; s < s1; s += 64) {
        const float ex = expf(att_p[s] - mx);
        att_p[s] = ex;
        sum += ex;
    }
    #pragma unroll
    for (int off = 32; off; off >>= 1) sum += __shfl_xor(sum, off);
    const float inv = 1.f / (sum + 1e-12f);
    for (int s = s0 + lane; s < s1; s += 64) att_p[s] *= inv;
}

// ============================================================
// H_enc[row] = sum att * H[col] ; writes Hcat (f32), Hcatbf (bf16), d_out copy
// ============================================================
__global__ __launch_bounds__(256) void gate_spmm_henc(
    const int* __restrict__ rowptr, const int* __restrict__ col_p,
    const float* __restrict__ att_p, const float* __restrict__ H,
    float* __restrict__ Hcat, unsigned short* __restrict__ Hcatbf,
    float* __restrict__ outp, int voff)
{
    const int row = blockIdx.x, d = threadIdx.x;
    const int s0 = rowptr[row], s1 = rowptr[row + 1];
    float acc = 0.f;
    for (int s = s0; s < s1; ++s)
        acc = fmaf(att_p[s], H[(size_t)col_p[s] * DH + d], acc);
    Hcat[(size_t)row * 512 + voff + d] = acc;
    Hcatbf[(size_t)row * 512 + voff + d] = f2bf(acc);
    outp[(size_t)row * DH + d] = acc;
}

// ============================================================
// PHC[row] = sum att * HC[col]  (256-wide gather), bf16 out
// ============================================================
__global__ __launch_bounds__(256) void gate_spmm_phc(
    const int* __restrict__ rowptr, const int* __restrict__ col_p,
    const float* __restrict__ att_p, const float* __restrict__ HCcat,
    int voff, unsigned short* __restrict__ PHCbf)
{
    const int row = blockIdx.x, d = threadIdx.x;
    const int s0 = rowptr[row], s1 = rowptr[row + 1];
    float acc = 0.f;
    for (int s = s0; s < s1; ++s)
        acc = fmaf(att_p[s], HCcat[(size_t)col_p[s] * 512 + voff + d], acc);
    PHCbf[(size_t)row * DH + d] = f2bf(acc);
}

// ============================================================
// coef write + S_Regular + Cq_loss + bf16(coef)
// ============================================================
__global__ __launch_bounds__(256) void gate_coef(
    const float* __restrict__ W, const float* __restrict__ Theta,
    float* __restrict__ coef_out, double* __restrict__ accumB,
    unsigned short* __restrict__ wbf)
{
    __shared__ float Ts[64][65];
    __shared__ float red[256];
    const int i0 = blockIdx.x * 64, j0 = blockIdx.y * 64;
    const int t = threadIdx.x;
    const int c = t & 63, rgrp = t >> 6;
    #pragma unroll
    for (int jj = 0; jj < 16; ++jj) {
        const int jr = rgrp * 16 + jj;
        Ts[jr][c] = Theta[(size_t)(j0 + jr) * NNODES + i0 + c];
    }
    __syncthreads();
    float sreg = 0.f, cq = 0.f;
    #pragma unroll
    for (int ii = 0; ii < 16; ++ii) {
        const int rr = rgrp * 16 + ii;
        const int gi = i0 + rr, gj = j0 + c;
        const float w = W[(size_t)gi * NNODES + gj];
        const float cf = (gi == gj) ? 0.f : w;
        coef_out[(size_t)gi * NNODES + gj] = cf;
        if (wbf) wbf[(size_t)gi * NNODES + gj] = f2bf(cf);
        const float a = fabsf(cf);
        sreg += a;
        cq = fmaf(a, fabsf(Ts[c][rr]), cq);
    }
    const int bucket = (blockIdx.x + blockIdx.y) & (NBUCKET - 1);
    red[t] = sreg; __syncthreads();
    for (int d = 128; d; d >>= 1) { if (t < d) red[t] += red[t + d]; __syncthreads(); }
    if (t == 0) atomicAdd(&accumB[bucket * AC_NUM + AC_SREG], (double)red[0]);
    __syncthreads();
    red[t] = cq; __syncthreads();
    for (int d = 128; d; d >>= 1) { if (t < d) red[t] += red[t + d]; __syncthreads(); }
    if (t == 0) atomicAdd(&accumB[bucket * AC_NUM + AC_CQ], (double)red[0]);
}

// ============================================================
// SE: sum((Hcat - HC)^2)
// ============================================================
__global__ __launch_bounds__(256) void gate_se(
    const float* __restrict__ Hcat, const float* __restrict__ HC,
    double* __restrict__ accumB)
{
    __shared__ float red[256];
    float part = 0.f;
    for (size_t i = (size_t)blockIdx.x * 256 + threadIdx.x;
         i < (size_t)NNODES * 512; i += (size_t)2048 * 256) {
        const float d = Hcat[i] - HC[i];
        part = fmaf(d, d, part);
    }
    const int t = threadIdx.x;
    red[t] = part; __syncthreads();
    for (int d = 128; d; d >>= 1) { if (t < d) red[t] += red[t + d]; __syncthreads(); }
    if (t == 0) atomicAdd(&accumB[(blockIdx.x & (NBUCKET - 1)) * AC_NUM + AC_SE], (double)red[0]);
}

// ============================================================
// consistent: sum((Henc1 - Henc2)^2)
// ============================================================
__global__ __launch_bounds__(256) void gate_cons(
    const float* __restrict__ Hcat, double* __restrict__ accumB)
{
    __shared__ float red[256];
    float part = 0.f;
    for (size_t i = (size_t)blockIdx.x * 256 + threadIdx.x;
         i < (size_t)NNODES * DH; i += (size_t)1024 * 256) {
        const size_t row = i >> 8;
        const int d = (int)(i & 255);
        const float v = Hcat[row * 512 + d] - Hcat[row * 512 + 256 + d];
        part = fmaf(v, v, part);
    }
    const int t = threadIdx.x;
    red[t] = part; __syncthreads();
    for (int d = 128; d; d >>= 1) { if (t < d) red[t] += red[t + d]; __syncthreads(); }
    if (t == 0) atomicAdd(&accumB[(blockIdx.x & (NBUCKET - 1)) * AC_NUM + AC_CONS], (double)red[0]);
}

// ============================================================
// structure loss: bf16 gathers from Hcatbf (half the traffic)
// ============================================================
__global__ __launch_bounds__(256) void gate_struct(
    const int* __restrict__ S, const int* __restrict__ R,
    const unsigned short* __restrict__ Hcatbf, int voff, double* __restrict__ accumB)
{
    __shared__ float red[4];
    const int wave = threadIdx.x >> 6, lane = threadIdx.x & 63;
    const int widx = blockIdx.x * 4 + wave;
    float part = 0.f;
    for (int e = widx; e < NEDGE; e += gridDim.x * 4) {
        const ushort4 av = ((const ushort4*)(Hcatbf + (size_t)S[e] * 512 + voff))[lane];
        const ushort4 bv = ((const ushort4*)(Hcatbf + (size_t)R[e] * 512 + voff))[lane];
        float d = bf2f(av.x) * bf2f(bv.x) + bf2f(av.y) * bf2f(bv.y)
                + bf2f(av.z) * bf2f(bv.z) + bf2f(av.w) * bf2f(bv.w);
        #pragma unroll
        for (int off = 32; off; off >>= 1) d += __shfl_xor(d, off);
        if (lane == 0) {
            const float x = d;
            const float sp = (x > 0.f) ? log1pf(expf(-x)) : (-x + log1pf(expf(x)));
            part += sp;
        }
    }
    if (lane == 0) red[wave] = part;
    __syncthreads();
    if (threadIdx.x == 0)
        atomicAdd(&accumB[(blockIdx.x & (NBUCKET - 1)) * AC_NUM + AC_STRUCT],
                  (double)(red[0] + red[1] + red[2] + red[3]));
}

// ============================================================
// final: sum buckets, combine, write scalar outputs
// ============================================================
__global__ void gate_final(const double* __restrict__ accumB, float* __restrict__ out)
{
    if (threadIdx.x == 0 && blockIdx.x == 0) {
        double acc[AC_NUM];
        for (int i = 0; i < AC_NUM; ++i) acc[i] = 0.0;
        for (int b = 0; b < NBUCKET; ++b)
            for (int i = 0; i < AC_NUM; ++i) acc[i] += accumB[b * AC_NUM + i];
        const double feat = acc[AC_FEAT], st = acc[AC_STRUCT];
        const double se = 0.5 * acc[AC_SE];
        const double cons = acc[AC_CONS], sreg = acc[AC_SREG];
        const double cq = acc[AC_CQ], dl = acc[AC_DENSE];
        const double pre = feat + st + 10.0 * se + 0.01 * cons + sreg;
        const double loss = 0.01 * feat + st + 10.0 * se + 0.001 * cons + sreg
                          + 5.0 * cq + 5.0 * dl;
        out[0] = (float)pre;
        out[1] = (float)loss;
        out[2] = (float)dl;
        out[3] = (float)feat;
        out[4] = (float)st;
        out[5] = (float)se;
        out[OFF_CONS] = (float)cons;
        out[OFF_SREG] = (float)sreg;
        out[OFF_CQ]   = (float)cq;
    }
}

// ============================================================
extern "C" void kernel_launch(void* const* d_in, const int* in_sizes, int n_in,
                              void* d_out, int out_size, void* d_ws, size_t ws_size,
                              hipStream_t stream)
{
    (void)in_sizes; (void)n_in; (void)out_size;
    const float* X      = (const float*)d_in[0];
    const float* X2     = (const float*)d_in[1];
    const float* Theta  = (const float*)d_in[2];
    const int*   Aidx   = (const int*)d_in[3];
    const int*   A2idx  = (const int*)d_in[5];
    const int*   S      = (const int*)d_in[7];
    const int*   R      = (const int*)d_in[8];
    const int*   S2     = (const int*)d_in[9];
    const int*   R2     = (const int*)d_in[10];
    const int*   p      = (const int*)d_in[11];
    const float* W0     = (const float*)d_in[13];
    const float* v00    = (const float*)d_in[14];
    const float* v10    = (const float*)d_in[15];
    const float* weight = (const float*)d_in[16];
    const float* fc1_w  = (const float*)d_in[17];
    const float* fc1_b  = (const float*)d_in[18];
    const float* fcz_w  = (const float*)d_in[19];
    const float* fcz_b  = (const float*)d_in[20];
    const float* fc2_w  = (const float*)d_in[21];
    const float* fc2_b  = (const float*)d_in[22];
    const float* fcz2_w = (const float*)d_in[23];
    const float* fcz2_b = (const float*)d_in[24];
    float* out = (float*)d_out;

    // ---- workspace carve ----
    char* wp = (char*)d_ws;
    auto alloc = [&](size_t bytes) -> void* {
        void* r = (void*)wp;
        wp += (bytes + 255) & ~(size_t)255;
        return r;
    };
    float* H1    = (float*)alloc((size_t)NNODES * DH * 4);
    float* H2    = (float*)alloc((size_t)NNODES * DH * 4);
    float* Hcat  = (float*)alloc((size_t)NNODES * 512 * 4);
    float* HCcat = (float*)alloc((size_t)NNODES * 512 * 4);
    unsigned short* Hcatbf = (unsigned short*)alloc((size_t)NNODES * 512 * 2);
    unsigned short* PHCbf  = (unsigned short*)alloc((size_t)NNODES * DH * 2);
    unsigned short* w0bf   = (unsigned short*)alloc((size_t)576 * DH * 2);
    float* zw1 = (float*)alloc((6 * DH + 8) * 4);
    float* zw2 = (float*)alloc((6 * DH + 8) * 4);
    float* f1a = (float*)alloc(NNODES * 4);
    float* f2a = (float*)alloc(NNODES * 4);
    float* f1b = (float*)alloc(NNODES * 4);
    float* f2b = (float*)alloc(NNODES * 4);
    int* cnt    = (int*)alloc(2 * NNODES * 4);
    int* rowptr = (int*)alloc(2 * (NNODES + 1) * 4);
    int* cur    = (int*)alloc(2 * NNODES * 4);
    int* colp   = (int*)alloc(2 * (size_t)NEDGE * 4);
    float* attp = (float*)alloc(2 * (size_t)NEDGE * 4);
    double* accumB = (double*)alloc(NBUCKET * AC_NUM * 8);
    // large MFMA scratch last (fallback check)
    unsigned short* Wbf = (unsigned short*)alloc((size_t)NNODES * NNODES * 2);
    unsigned short* Bt  = (unsigned short*)alloc((size_t)512 * NNODES * 2);
    const bool use_mfma = ((size_t)(wp - (char*)d_ws) <= ws_size);

    hipMemsetAsync(cnt, 0, 2 * NNODES * 4, stream);
    hipMemsetAsync(accumB, 0, NBUCKET * AC_NUM * 8, stream);

    // tiny precomputes (independent)
    gate_w0bf<<<576, 256, 0, stream>>>(W0, w0bf);
    gate_zfold<<<2, 256, 0, stream>>>(fc1_w, fc1_b, fcz_w, fcz_b,
                                      fc2_w, fc2_b, fcz2_w, fcz2_b, zw1, zw2);

    // encode: H = X @ W0 (both views, fp32 — feeds H_enc outputs)
    gate_gemm_nn<<<dim3(NNODES / 64, DH / 64), 256, 0, stream>>>(
        X, W0, H1, NNODES, DH, DIN, DIN, DH, DH);
    gate_gemm_nn<<<dim3(NNODES / 64, DH / 64), 256, 0, stream>>>(
        X2, W0, H2, NNODES, DH, DIN, DIN, DH, DH);
    gate_f1f2<<<NNODES / 4, 256, 0, stream>>>(H1, v00, v10, f1a, f2a);
    gate_f1f2<<<NNODES / 4, 256, 0, stream>>>(H2, v00, v10, f1b, f2b);

    // CSR build
    gate_hist<<<NEDGE / 256, 256, 0, stream>>>(Aidx, cnt);
    gate_hist<<<NEDGE / 256, 256, 0, stream>>>(A2idx, cnt + NNODES);
    gate_scan<<<1, 256, 0, stream>>>(cnt, rowptr, cur);
    gate_scan<<<1, 256, 0, stream>>>(cnt + NNODES, rowptr + NNODES + 1, cur + NNODES);
    gate_scatter<<<NEDGE / 256, 256, 0, stream>>>(Aidx, Aidx + NEDGE, cur, colp);
    gate_scatter<<<NEDGE / 256, 256, 0, stream>>>(A2idx, A2idx + NEDGE, cur + NNODES, colp + NEDGE);

    // attention + aggregation
    gate_att<<<NNODES, 64, 0, stream>>>(rowptr, colp, f1a, f2a, attp);
    gate_att<<<NNODES, 64, 0, stream>>>(rowptr + NNODES + 1, colp + NEDGE, f1b, f2b, attp + NEDGE);
    gate_spmm_henc<<<NNODES, 256, 0, stream>>>(rowptr, colp, attp, H1, Hcat, Hcatbf,
                                               out + OFF_H1, 0);
    gate_spmm_henc<<<NNODES, 256, 0, stream>>>(rowptr + NNODES + 1, colp + NEDGE, attp + NEDGE,
                                               H2, Hcat, Hcatbf, out + OFF_H2, 256);

    // coef write + S_Regular + Cq (+ bf16 coef)
    gate_coef<<<dim3(NNODES / 64, NNODES / 64), 256, 0, stream>>>(
        weight, Theta, out + OFF_COEF, accumB, use_mfma ? Wbf : nullptr);

    // HC = coef @ [Henc1 | Henc2]
    if (use_mfma) {
        gate_hcat_bt<<<dim3(NNODES / 64, 512 / 64), 256, 0, stream>>>(Hcat, Bt);
        gate_gemm_coef_mfma<<<dim3(NNODES / BMT, 512 / BNT), 256, 0, stream>>>(Wbf, Bt, HCcat);
    } else {
        gate_gemm_coef<<<dim3(NNODES / 128, 512 / 64), 256, 0, stream>>>(weight, Hcat, HCcat);
    }

    gate_se<<<2048, 256, 0, stream>>>(Hcat, HCcat, accumB);
    gate_cons<<<1024, 256, 0, stream>>>(Hcat, accumB);

    // features loss: PHC = spmm(att, HC); feat += (X - PHC @ W0^T)^2  (fused)
    gate_spmm_phc<<<NNODES, 256, 0, stream>>>(rowptr, colp, attp, HCcat, 0, PHCbf);
    gate_mfma_recon<<<dim3(NNODES / BMT, 576 / BNT), 256, 0, stream>>>(PHCbf, w0bf, X, accumB);
    gate_spmm_phc<<<NNODES, 256, 0, stream>>>(rowptr + NNODES + 1, colp + NEDGE, attp + NEDGE,
                                              HCcat, 256, PHCbf);
    gate_mfma_recon<<<dim3(NNODES / BMT, 576 / BNT), 256, 0, stream>>>(PHCbf, w0bf, X2, accumB);

    // dense heads (folded)
    gate_zhead2<<<NNODES / 4, 256, 0, stream>>>(Hcat, 0, zw1, p, accumB);
    gate_zhead2<<<NNODES / 4, 256, 0, stream>>>(Hcat, 256, zw2, p, accumB);

    // structure losses (bf16 gathers)
    gate_struct<<<2048, 256, 0, stream>>>(S, R, Hcatbf, 0, accumB);
    gate_struct<<<2048, 256, 0, stream>>>(S2, R2, Hcatbf, 256, accumB);

    gate_final<<<1, 64, 0, stream>>>(accumB, out);
}